// Round 8
// baseline (1140.900 us; speedup 1.0000x reference)
//
#include <hip/hip_runtime.h>
#include <math.h>

#define BB 4
#define TT 4096
#define DD 768
#define SS 1024
#define S2 2048
#define KTOP 8
#define RWEIGHT 0.1f
#define TAU 2e-4f
#define AMB_CAP 64

typedef __attribute__((ext_vector_type(8))) _Float16 f16x8;
typedef __attribute__((ext_vector_type(4))) float f32x4;
typedef _Float16 f16;

// ---------------------------------------------------------------------------
// build_pooled: slots[0:S] = window-mean(4) of x (per batch).
// ---------------------------------------------------------------------------
__global__ __launch_bounds__(256) void build_pooled(
    const float* __restrict__ x, float* __restrict__ slots)
{
    int i = blockIdx.x * 256 + threadIdx.x;      // over S*D = 786432
    int s = i / DD;
    int d = i - s * DD;
    const float* xb = x + (size_t)(4 * s) * DD + d;
    slots[i] = 0.25f * (xb[0] + xb[DD] + xb[2 * DD] + xb[3 * DD]);
}

// copy_pm: slots[S:2S] = pm (once; batch-invariant).
__global__ __launch_bounds__(256) void copy_pm(
    const float* __restrict__ pm, float* __restrict__ slots)
{
    int i = blockIdx.x * 256 + threadIdx.x;
    slots[(size_t)SS * DD + i] = pm[i];
}

// ---------------------------------------------------------------------------
// transpose_all: 4 weight matrices in one launch (z = which).
// ---------------------------------------------------------------------------
__global__ __launch_bounds__(256) void transpose_all(
    const float* __restrict__ W0, const float* __restrict__ W1,
    const float* __restrict__ W2, const float* __restrict__ W3,
    float* __restrict__ T0, float* __restrict__ T1,
    float* __restrict__ T2, float* __restrict__ T3)
{
    const float* W = (blockIdx.z == 0) ? W0 : (blockIdx.z == 1) ? W1
                   : (blockIdx.z == 2) ? W2 : W3;
    float* WT = (blockIdx.z == 0) ? T0 : (blockIdx.z == 1) ? T1
              : (blockIdx.z == 2) ? T2 : T3;
    __shared__ float t[32][33];
    int bx = blockIdx.x * 32, by = blockIdx.y * 32;
    int lx = threadIdx.x & 31, ly = threadIdx.x >> 5;   // 32 x 8
#pragma unroll
    for (int r = 0; r < 32; r += 8)
        t[ly + r][lx] = W[(size_t)(bx + ly + r) * 768 + by + lx];
    __syncthreads();
#pragma unroll
    for (int r = 0; r < 32; r += 8)
        WT[(size_t)(by + ly + r) * 768 + bx + lx] = t[lx][ly + r];
}

__global__ void zeroN(int* p) { p[threadIdx.x] = 0; }

// ---------------------------------------------------------------------------
// Conflict-free staging geometry (both MFMA kernels):
//   thread: srow = tid>>1, c0 = tid&1; owns chunks {c0, c0+2} of the 32-wide
//   k-slice (chunk = 8 f16 = 16B granule).
//   store pos p(c,r) = c ^ (r&3) ^ ((r>>2)&1)  -> every 16-lane group of every
//   ds_write/ds_read covers all 8 LDS granules exactly twice (wave64 floor).
//   read swizzle csw = ((l>>4) ^ (l&3) ^ ((l>>2)&1))*8.
// ---------------------------------------------------------------------------

// 3-pass f16-split MFMA NT GEMM (selection path: q, k, scores).
__global__ __launch_bounds__(256) void mfma_nt_split(
    const float* __restrict__ A, const float* __restrict__ B,
    const float* __restrict__ bias, float* __restrict__ C,
    int N, float alpha, float bscale)
{
    __shared__ f16 Ah[128 * 32], Am[128 * 32], Bh[128 * 32], Bm[128 * 32];
    const int tid = threadIdx.x;
    const int lane = tid & 63;
    const int wc = (tid >> 6) & 1;
    const int wr = (tid >> 7) & 1;
    const size_t bm = (size_t)blockIdx.y * 128;
    const size_t bn = (size_t)blockIdx.x * 128;

    f32x4 acc[4][4];
#pragma unroll
    for (int i = 0; i < 4; ++i)
#pragma unroll
        for (int j = 0; j < 4; ++j) acc[i][j] = (f32x4){0.f, 0.f, 0.f, 0.f};

    const int srow = tid >> 1;
    const int c0 = tid & 1;
    const float* pa = A + (bm + srow) * 768 + c0 * 8;
    const float* pb = B + (bn + srow) * 768 + c0 * 8;
    const int p0 = c0 ^ (srow & 3) ^ ((srow >> 2) & 1);
    const int wo0 = srow * 32 + p0 * 8;
    const int wo1 = wo0 ^ 16;
    const int csw = (((lane >> 4) ^ (lane & 3) ^ ((lane >> 2) & 1)) * 8);

    for (int k0 = 0; k0 < 768; k0 += 32) {
        float4 a0 = *(const float4*)(pa + k0);
        float4 a1 = *(const float4*)(pa + k0 + 4);
        float4 a2 = *(const float4*)(pa + k0 + 16);
        float4 a3 = *(const float4*)(pa + k0 + 20);
        float4 b0 = *(const float4*)(pb + k0);
        float4 b1 = *(const float4*)(pb + k0 + 4);
        float4 b2 = *(const float4*)(pb + k0 + 16);
        float4 b3 = *(const float4*)(pb + k0 + 20);
        __syncthreads();
        {
            float av[16] = {a0.x, a0.y, a0.z, a0.w, a1.x, a1.y, a1.z, a1.w,
                            a2.x, a2.y, a2.z, a2.w, a3.x, a3.y, a3.z, a3.w};
            float bv[16] = {b0.x, b0.y, b0.z, b0.w, b1.x, b1.y, b1.z, b1.w,
                            b2.x, b2.y, b2.z, b2.w, b3.x, b3.y, b3.z, b3.w};
            f16x8 h, m;
#pragma unroll
            for (int j = 0; j < 8; ++j) {
                f16 hh = (f16)av[j]; h[j] = hh; m[j] = (f16)(av[j] - (float)hh);
            }
            *(f16x8*)&Ah[wo0] = h; *(f16x8*)&Am[wo0] = m;
#pragma unroll
            for (int j = 0; j < 8; ++j) {
                f16 hh = (f16)av[j + 8]; h[j] = hh; m[j] = (f16)(av[j + 8] - (float)hh);
            }
            *(f16x8*)&Ah[wo1] = h; *(f16x8*)&Am[wo1] = m;
#pragma unroll
            for (int j = 0; j < 8; ++j) {
                f16 hh = (f16)bv[j]; h[j] = hh; m[j] = (f16)(bv[j] - (float)hh);
            }
            *(f16x8*)&Bh[wo0] = h; *(f16x8*)&Bm[wo0] = m;
#pragma unroll
            for (int j = 0; j < 8; ++j) {
                f16 hh = (f16)bv[j + 8]; h[j] = hh; m[j] = (f16)(bv[j + 8] - (float)hh);
            }
            *(f16x8*)&Bh[wo1] = h; *(f16x8*)&Bm[wo1] = m;
        }
        __syncthreads();

        f16x8 fah[4], fam[4], fbh[4], fbm[4];
#pragma unroll
        for (int mi = 0; mi < 4; ++mi) {
            int off = (wr * 64 + mi * 16 + (lane & 15)) * 32 + csw;
            fah[mi] = *(const f16x8*)&Ah[off];
            fam[mi] = *(const f16x8*)&Am[off];
        }
#pragma unroll
        for (int ni = 0; ni < 4; ++ni) {
            int off = (wc * 64 + ni * 16 + (lane & 15)) * 32 + csw;
            fbh[ni] = *(const f16x8*)&Bh[off];
            fbm[ni] = *(const f16x8*)&Bm[off];
        }
#pragma unroll
        for (int mi = 0; mi < 4; ++mi)
#pragma unroll
            for (int ni = 0; ni < 4; ++ni) {
                acc[mi][ni] = __builtin_amdgcn_mfma_f32_16x16x32_f16(
                    fah[mi], fbh[ni], acc[mi][ni], 0, 0, 0);
                acc[mi][ni] = __builtin_amdgcn_mfma_f32_16x16x32_f16(
                    fah[mi], fbm[ni], acc[mi][ni], 0, 0, 0);
                acc[mi][ni] = __builtin_amdgcn_mfma_f32_16x16x32_f16(
                    fam[mi], fbh[ni], acc[mi][ni], 0, 0, 0);
            }
    }

    const int orow0 = wr * 64 + (lane >> 4) * 4;
    const int ocol0 = wc * 64 + (lane & 15);
#pragma unroll
    for (int mi = 0; mi < 4; ++mi)
#pragma unroll
        for (int ni = 0; ni < 4; ++ni) {
            size_t col = bn + ocol0 + ni * 16;
            float badd = bias ? bscale * bias[col] : 0.f;
            size_t rbase = bm + orow0 + mi * 16;
#pragma unroll
            for (int r = 0; r < 4; ++r)
                C[(rbase + r) * N + col] = alpha * acc[mi][ni][r] + badd;
        }
}

// 1-pass f16 MFMA NT GEMM (value path: v, proj).
__global__ __launch_bounds__(256) void mfma_nt_f16(
    const float* __restrict__ A, const float* __restrict__ B,
    const float* __restrict__ bias, float* __restrict__ C,
    int N, float alpha, float bscale)
{
    __shared__ f16 Ah[128 * 32], Bh[128 * 32];
    const int tid = threadIdx.x;
    const int lane = tid & 63;
    const int wc = (tid >> 6) & 1;
    const int wr = (tid >> 7) & 1;
    const size_t bm = (size_t)blockIdx.y * 128;
    const size_t bn = (size_t)blockIdx.x * 128;

    f32x4 acc[4][4];
#pragma unroll
    for (int i = 0; i < 4; ++i)
#pragma unroll
        for (int j = 0; j < 4; ++j) acc[i][j] = (f32x4){0.f, 0.f, 0.f, 0.f};

    const int srow = tid >> 1;
    const int c0 = tid & 1;
    const float* pa = A + (bm + srow) * 768 + c0 * 8;
    const float* pb = B + (bn + srow) * 768 + c0 * 8;
    const int p0 = c0 ^ (srow & 3) ^ ((srow >> 2) & 1);
    const int wo0 = srow * 32 + p0 * 8;
    const int wo1 = wo0 ^ 16;
    const int csw = (((lane >> 4) ^ (lane & 3) ^ ((lane >> 2) & 1)) * 8);

    for (int k0 = 0; k0 < 768; k0 += 32) {
        float4 a0 = *(const float4*)(pa + k0);
        float4 a1 = *(const float4*)(pa + k0 + 4);
        float4 a2 = *(const float4*)(pa + k0 + 16);
        float4 a3 = *(const float4*)(pa + k0 + 20);
        float4 b0 = *(const float4*)(pb + k0);
        float4 b1 = *(const float4*)(pb + k0 + 4);
        float4 b2 = *(const float4*)(pb + k0 + 16);
        float4 b3 = *(const float4*)(pb + k0 + 20);
        __syncthreads();
        {
            f16x8 h;
            h[0] = (f16)a0.x; h[1] = (f16)a0.y; h[2] = (f16)a0.z; h[3] = (f16)a0.w;
            h[4] = (f16)a1.x; h[5] = (f16)a1.y; h[6] = (f16)a1.z; h[7] = (f16)a1.w;
            *(f16x8*)&Ah[wo0] = h;
            h[0] = (f16)a2.x; h[1] = (f16)a2.y; h[2] = (f16)a2.z; h[3] = (f16)a2.w;
            h[4] = (f16)a3.x; h[5] = (f16)a3.y; h[6] = (f16)a3.z; h[7] = (f16)a3.w;
            *(f16x8*)&Ah[wo1] = h;
            h[0] = (f16)b0.x; h[1] = (f16)b0.y; h[2] = (f16)b0.z; h[3] = (f16)b0.w;
            h[4] = (f16)b1.x; h[5] = (f16)b1.y; h[6] = (f16)b1.z; h[7] = (f16)b1.w;
            *(f16x8*)&Bh[wo0] = h;
            h[0] = (f16)b2.x; h[1] = (f16)b2.y; h[2] = (f16)b2.z; h[3] = (f16)b2.w;
            h[4] = (f16)b3.x; h[5] = (f16)b3.y; h[6] = (f16)b3.z; h[7] = (f16)b3.w;
            *(f16x8*)&Bh[wo1] = h;
        }
        __syncthreads();

        f16x8 fah[4], fbh[4];
#pragma unroll
        for (int mi = 0; mi < 4; ++mi)
            fah[mi] = *(const f16x8*)&Ah[(wr * 64 + mi * 16 + (lane & 15)) * 32 + csw];
#pragma unroll
        for (int ni = 0; ni < 4; ++ni)
            fbh[ni] = *(const f16x8*)&Bh[(wc * 64 + ni * 16 + (lane & 15)) * 32 + csw];
#pragma unroll
        for (int mi = 0; mi < 4; ++mi)
#pragma unroll
            for (int ni = 0; ni < 4; ++ni)
                acc[mi][ni] = __builtin_amdgcn_mfma_f32_16x16x32_f16(
                    fah[mi], fbh[ni], acc[mi][ni], 0, 0, 0);
    }

    const int orow0 = wr * 64 + (lane >> 4) * 4;
    const int ocol0 = wc * 64 + (lane & 15);
#pragma unroll
    for (int mi = 0; mi < 4; ++mi)
#pragma unroll
        for (int ni = 0; ni < 4; ++ni) {
            size_t col = bn + ocol0 + ni * 16;
            float badd = bias ? bscale * bias[col] : 0.f;
            size_t rbase = bm + orow0 + mi * 16;
#pragma unroll
            for (int r = 0; r < 4; ++r)
                C[(rbase + r) * N + col] = alpha * acc[mi][ni][r] + badd;
        }
}

// ---------------------------------------------------------------------------
// select_combine: one wave per row. top-9 (extended to 16 iff ambiguous);
// gap test appends row + its top-16 candidates; softmax top-8; combine.
// ---------------------------------------------------------------------------
__global__ __launch_bounds__(256) void select_combine(
    const float* __restrict__ scores, const float* __restrict__ v,
    float* __restrict__ retrc,
    int* __restrict__ amb_count, int* __restrict__ amb_rows,
    int* __restrict__ cand)
{
    const int lane = threadIdx.x & 63;
    const int wave = threadIdx.x >> 6;
    const int row = blockIdx.x * 4 + wave;

    const float* srow = scores + (size_t)row * S2;
    float vals[32];
#pragma unroll
    for (int i = 0; i < 32; ++i) vals[i] = srow[lane + (i << 6)];

    float topv[16]; int topi[16];
    bool amb = false;
    int nr = 9;
    for (int r = 0; r < 16; ++r) {
        if (r >= nr) break;
        float bvv = -3.4e38f; int bii = 0x7fffffff;
#pragma unroll
        for (int i = 0; i < 32; ++i)
            if (vals[i] > bvv) { bvv = vals[i]; bii = lane + (i << 6); }
#pragma unroll
        for (int off = 32; off > 0; off >>= 1) {
            float ov = __shfl_xor(bvv, off);
            int   oi = __shfl_xor(bii, off);
            if (ov > bvv || (ov == bvv && oi < bii)) { bvv = ov; bii = oi; }
        }
        topv[r] = bvv; topi[r] = bii;
        if ((bii & 63) == lane) vals[bii >> 6] = -3.4e38f;
        if (r == 8) {
            amb = (topv[7] - topv[8]) < TAU;   // wave-uniform
            if (amb) nr = 16;
        }
    }

    if (amb) {
        int idx = 0;
        if (lane == 0) idx = atomicAdd(amb_count, 1);
        idx = __shfl(idx, 0);
        if (idx < AMB_CAP) {
            if (lane == 0) amb_rows[idx] = row;
            if (lane < 16) cand[idx * 16 + lane] = topi[lane];
        }
    }

    float m = topv[0], w[KTOP], sum = 0.f;
#pragma unroll
    for (int r = 0; r < KTOP; ++r) { w[r] = expf(topv[r] - m); sum += w[r]; }
    float inv = 1.f / sum;

    const float4* v4 = (const float4*)v;
    float4* o4 = (float4*)(retrc + (size_t)row * DD);
#pragma unroll
    for (int c = 0; c < 3; ++c) {
        int col = c * 64 + lane;
        float4 accv = {0.f, 0.f, 0.f, 0.f};
#pragma unroll
        for (int r = 0; r < KTOP; ++r) {
            float4 vv = v4[(size_t)topi[r] * (DD / 4) + col];
            float wr = w[r] * inv;
            accv.x += wr * vv.x; accv.y += wr * vv.y;
            accv.z += wr * vv.z; accv.w += wr * vv.w;
        }
        o4[col] = accv;
    }
}

// ---------------------------------------------------------------------------
// F1: q64[i][j] = f64(x_row . Wq[:,j]) + bq[j].  grid (12, AMB_CAP).
// ---------------------------------------------------------------------------
__global__ __launch_bounds__(256) void fixup_q(
    const int* __restrict__ amb_count, const int* __restrict__ amb_rows,
    const float* __restrict__ xc, const float* __restrict__ Wq,
    const float* __restrict__ bq, double* __restrict__ q64buf)
{
    int n = *amb_count; if (n > AMB_CAP) n = AMB_CAP;
    const int i = blockIdx.y;
    if (i >= n) return;
    const int tid = threadIdx.x;
    const int jl = tid & 63;
    const int ks = tid >> 6;
    const int j = blockIdx.x * 64 + jl;
    const int row = amb_rows[i];

    __shared__ float xs[768];
    __shared__ double ps[4][64];
    for (int t = tid; t < 768; t += 256) xs[t] = xc[(size_t)row * 768 + t];
    __syncthreads();

    double a0 = 0.0, a1 = 0.0;
    const float* wp = Wq + j;
    const int k0 = ks * 192;
#pragma unroll 8
    for (int k = 0; k < 192; k += 2) {
        a0 = fma((double)xs[k0 + k],     (double)wp[(size_t)(k0 + k) * 768],     a0);
        a1 = fma((double)xs[k0 + k + 1], (double)wp[(size_t)(k0 + k + 1) * 768], a1);
    }
    ps[ks][jl] = a0 + a1;
    __syncthreads();
    if (ks == 0)
        q64buf[(size_t)i * 768 + j] =
            ((ps[0][jl] + ps[1][jl]) + (ps[2][jl] + ps[3][jl])) + (double)bq[j];
}

// ---------------------------------------------------------------------------
// F2: u[i][t] = sum_j WkT[j][t] * q64[i][j].  grid (12, AMB_CAP).
// ---------------------------------------------------------------------------
__global__ __launch_bounds__(256) void fixup_u(
    const int* __restrict__ amb_count,
    const float* __restrict__ WkT, const float* __restrict__ bk,
    const double* __restrict__ q64buf,
    double* __restrict__ ubuf, double* __restrict__ bkqbuf)
{
    int n = *amb_count; if (n > AMB_CAP) n = AMB_CAP;
    const int i = blockIdx.y;
    if (i >= n) return;
    const int tid = threadIdx.x;
    const int tl = tid & 63;
    const int js = tid >> 6;
    const int t = blockIdx.x * 64 + tl;

    __shared__ double qs[768];
    __shared__ double ps[4][64];
    const double* qrow = q64buf + (size_t)i * 768;
    for (int k = tid; k < 768; k += 256) qs[k] = qrow[k];
    __syncthreads();

    double a0 = 0.0, a1 = 0.0;
    const float* wp = WkT + t;
    const int j0 = js * 192;
#pragma unroll 8
    for (int k = 0; k < 192; k += 2) {
        a0 = fma((double)wp[(size_t)(j0 + k) * 768],     qs[j0 + k],     a0);
        a1 = fma((double)wp[(size_t)(j0 + k + 1) * 768], qs[j0 + k + 1], a1);
    }
    ps[js][tl] = a0 + a1;
    __syncthreads();
    if (js == 0)
        ubuf[(size_t)i * 768 + t] = (ps[0][tl] + ps[1][tl]) + (ps[2][tl] + ps[3][tl]);

    if (blockIdx.x == 0 && tid < 64) {
        double p = 0.0;
#pragma unroll
        for (int c = 0; c < 12; ++c) {
            int jj = tid + (c << 6);
            p = fma((double)bk[jj], qs[jj], p);
        }
#pragma unroll
        for (int off = 32; off; off >>= 1) p += __shfl_xor(p, off);
        if (tid == 0) bkqbuf[i] = p;
    }
}

// ---------------------------------------------------------------------------
// F3: per amb row: 16 exact scores, f64 top-8 (val desc, idx asc), f64
// softmax, combine, overwrite retr row. grid (AMB_CAP).
// ---------------------------------------------------------------------------
__global__ __launch_bounds__(256) void fixup_sel(
    const int* __restrict__ amb_count, const int* __restrict__ amb_rows,
    const float* __restrict__ xb, const float* __restrict__ pm,
    const int* __restrict__ cand, const double* __restrict__ ubuf,
    const double* __restrict__ bkqbuf, const float* __restrict__ v,
    float* __restrict__ retrc)
{
    int n = *amb_count; if (n > AMB_CAP) n = AMB_CAP;
    const int i = blockIdx.x;
    if (i >= n) return;
    const int tid = threadIdx.x;
    const int lane = tid & 63;
    const int wave = tid >> 6;
    const int row = amb_rows[i];

    __shared__ double us[768];
    __shared__ double cs_s[16];
    __shared__ float wsm[KTOP];
    __shared__ int seli[KTOP];

    const double* urow = ubuf + (size_t)i * 768;
    for (int t = tid; t < 768; t += 256) us[t] = urow[t];
    __syncthreads();

    const double ISQ = 1.0 / sqrt((double)DD);
    const double bkq = bkqbuf[i];
#pragma unroll
    for (int c = wave; c < 16; c += 4) {
        int s = cand[i * 16 + c];
        double p = 0.0;
        if (s < SS) {
            const float* xr = xb + (size_t)(4 * s) * 768;
#pragma unroll
            for (int t = 0; t < 12; ++t) {
                int j2 = lane + (t << 6);
                double sv = 0.25 * ((double)xr[j2] + (double)xr[j2 + 768] +
                                    (double)xr[j2 + 1536] + (double)xr[j2 + 2304]);
                p = fma(sv, us[j2], p);
            }
        } else {
            const float* pr = pm + (size_t)(s - SS) * 768;
#pragma unroll
            for (int t = 0; t < 12; ++t) {
                int j2 = lane + (t << 6);
                p = fma((double)pr[j2], us[j2], p);
            }
        }
#pragma unroll
        for (int off = 32; off; off >>= 1) p += __shfl_xor(p, off);
        if (lane == 0) cs_s[c] = (p + bkq) * ISQ;
    }
    __syncthreads();

    if (tid == 0) {
        double cs[16]; int ci[16];
        for (int c = 0; c < 16; ++c) { cs[c] = cs_s[c]; ci[c] = cand[i * 16 + c]; }
        unsigned used = 0;
        double sv[KTOP]; int sx[KTOP];
        for (int r = 0; r < KTOP; ++r) {
            int bi = -1;
            for (int c = 0; c < 16; ++c) {
                if (used & (1u << c)) continue;
                if (bi < 0 || cs[c] > cs[bi] ||
                    (cs[c] == cs[bi] && ci[c] < ci[bi])) bi = c;
            }
            used |= (1u << bi); sv[r] = cs[bi]; sx[r] = ci[bi];
        }
        double mx = sv[0], es[KTOP], ssum = 0.0;
        for (int r = 0; r < KTOP; ++r) { es[r] = exp(sv[r] - mx); ssum += es[r]; }
        for (int r = 0; r < KTOP; ++r) { wsm[r] = (float)(es[r] / ssum); seli[r] = sx[r]; }
    }
    __syncthreads();
    for (int j = tid; j < 768; j += 256) {
        float o = 0.f;
#pragma unroll
        for (int r = 0; r < KTOP; ++r) o += wsm[r] * v[(size_t)seli[r] * 768 + j];
        retrc[(size_t)row * 768 + j] = o;
    }
}

// ---------------------------------------------------------------------------
extern "C" void kernel_launch(void* const* d_in, const int* in_sizes, int n_in,
                              void* d_out, int out_size, void* d_ws, size_t ws_size,
                              hipStream_t stream)
{
    const float* x  = (const float*)d_in[0];
    const float* Wq = (const float*)d_in[1];
    const float* bq = (const float*)d_in[2];
    const float* Wk = (const float*)d_in[3];
    const float* bk = (const float*)d_in[4];
    const float* Wv = (const float*)d_in[5];
    const float* bv = (const float*)d_in[6];
    const float* Wp = (const float*)d_in[7];
    const float* bp = (const float*)d_in[8];
    const float* pm = (const float*)d_in[9];
    float* out = (float*)d_out;
    float* ws  = (float*)d_ws;

    const float inv_sqrt_d = (float)(1.0 / sqrt((double)DD));
    const size_t TD  = (size_t)TT * DD;
    const size_t SD2 = (size_t)S2 * DD;
    const size_t WSZ = (size_t)DD * DD;

    float* p = ws;
    float* WqT = p; p += WSZ;
    float* WkT = p; p += WSZ;
    float* WvT = p; p += WSZ;
    float* WpT = p; p += WSZ;
    float* slots = p; p += SD2;
    float* q32 = p; p += TD;
    float* k32 = p; p += SD2;
    float* v32 = p; p += SD2;
    float* retr = p; p += TD;
    double* q64buf = (double*)p; p += (size_t)AMB_CAP * DD * 2;
    double* ubuf   = (double*)p; p += (size_t)AMB_CAP * DD * 2;
    double* bkqbuf = (double*)p; p += AMB_CAP * 2;
    int* cand = (int*)p; p += (size_t)AMB_CAP * 16;
    int* ambc = (int*)p; p += 64;
    int* ambrows = (int*)p; p += AMB_CAP;
    float* scores = p;
    size_t used = (size_t)(p - ws);

    long tc = TT;
    while (tc > 512 && (used + (size_t)tc * S2) * 4 > ws_size) tc >>= 1;

    transpose_all<<<dim3(24, 24, 4), 256, 0, stream>>>(
        Wq, Wk, Wv, Wp, WqT, WkT, WvT, WpT);
    zeroN<<<1, 64, 0, stream>>>(ambc);

    // batch-invariant halves: slots[S:2S] = pm; k32/v32 rows [S:2S).
    copy_pm<<<(SS * DD) / 256, 256, 0, stream>>>(pm, slots);
    mfma_nt_split<<<dim3(6, 8), 256, 0, stream>>>(
        slots + (size_t)SS * DD, WkT, bk, k32 + (size_t)SS * DD, DD, 1.f, 1.f);
    mfma_nt_f16<<<dim3(6, 8), 256, 0, stream>>>(
        slots + (size_t)SS * DD, WvT, bv, v32 + (size_t)SS * DD, DD, 1.f, 1.f);

    int cidx = 0;
    for (int b = 0; b < BB; ++b) {
        const float* xb = x + (size_t)b * TD;
        build_pooled<<<(SS * DD) / 256, 256, 0, stream>>>(xb, slots);
        mfma_nt_split<<<dim3(6, 32), 256, 0, stream>>>(
            xb, WqT, bq, q32, DD, 1.f, 1.f);
        mfma_nt_split<<<dim3(6, 8), 256, 0, stream>>>(
            slots, WkT, bk, k32, DD, 1.f, 1.f);
        mfma_nt_f16<<<dim3(6, 8), 256, 0, stream>>>(
            slots, WvT, bv, v32, DD, 1.f, 1.f);

        for (long t0 = 0; t0 < TT; t0 += tc) {
            int* cc = ambc + cidx; cidx = (cidx + 1) & 63;
            mfma_nt_split<<<dim3(16, tc / 128), 256, 0, stream>>>(
                q32 + (size_t)t0 * DD, k32, (const float*)nullptr, scores,
                S2, inv_sqrt_d, 0.f);
            select_combine<<<tc / 4, 256, 0, stream>>>(
                scores, v32, retr + (size_t)t0 * DD, cc, ambrows, cand);
            fixup_q<<<dim3(12, AMB_CAP), 256, 0, stream>>>(
                cc, ambrows, xb + (size_t)t0 * DD, Wq, bq, q64buf);
            fixup_u<<<dim3(12, AMB_CAP), 256, 0, stream>>>(
                cc, WkT, bk, q64buf, ubuf, bkqbuf);
            fixup_sel<<<AMB_CAP, 256, 0, stream>>>(
                cc, ambrows, xb, pm, cand, ubuf, bkqbuf, v32,
                retr + (size_t)t0 * DD);
        }

        mfma_nt_f16<<<dim3(6, 32), 256, 0, stream>>>(
            retr, WpT, bp, out + (size_t)b * TD, DD, RWEIGHT, RWEIGHT);
    }
}

// Round 9
// 706.104 us; speedup vs baseline: 1.6158x; 1.6158x over previous
//
#include <hip/hip_runtime.h>
#include <math.h>

#define BB 4
#define TT 4096
#define DD 768
#define SS 1024
#define S2 2048
#define KTOP 8
#define RWEIGHT 0.1f
#define TAU 2e-4f
#define AMB_CAP 64

typedef __attribute__((ext_vector_type(8))) _Float16 f16x8;
typedef __attribute__((ext_vector_type(4))) float f32x4;
typedef _Float16 f16;

// ---------------------------------------------------------------------------
// build_pooled_all: pooled slots for ALL batches. [B*S][D]
// ---------------------------------------------------------------------------
__global__ __launch_bounds__(256) void build_pooled_all(
    const float* __restrict__ x, float* __restrict__ slots)
{
    int i = blockIdx.x * 256 + threadIdx.x;     // over B*S*D = 3145728
    int s2 = i / DD;
    int d = i - s2 * DD;
    int b = s2 >> 10, s = s2 & 1023;
    const float* xb = x + (size_t)b * TT * DD + (size_t)(4 * s) * DD + d;
    slots[i] = 0.25f * (xb[0] + xb[DD] + xb[2 * DD] + xb[3 * DD]);
}

// ---------------------------------------------------------------------------
__global__ __launch_bounds__(256) void transpose_all(
    const float* __restrict__ W0, const float* __restrict__ W1,
    const float* __restrict__ W2, const float* __restrict__ W3,
    float* __restrict__ T0, float* __restrict__ T1,
    float* __restrict__ T2, float* __restrict__ T3)
{
    const float* W = (blockIdx.z == 0) ? W0 : (blockIdx.z == 1) ? W1
                   : (blockIdx.z == 2) ? W2 : W3;
    float* WT = (blockIdx.z == 0) ? T0 : (blockIdx.z == 1) ? T1
              : (blockIdx.z == 2) ? T2 : T3;
    __shared__ float t[32][33];
    int bx = blockIdx.x * 32, by = blockIdx.y * 32;
    int lx = threadIdx.x & 31, ly = threadIdx.x >> 5;
#pragma unroll
    for (int r = 0; r < 32; r += 8)
        t[ly + r][lx] = W[(size_t)(bx + ly + r) * 768 + by + lx];
    __syncthreads();
#pragma unroll
    for (int r = 0; r < 32; r += 8)
        WT[(size_t)(by + ly + r) * 768 + bx + lx] = t[lx][ly + r];
}

__global__ void zeroN(int* p) { p[threadIdx.x] = 0; }

// ---------------------------------------------------------------------------
// producers: merged per-batch GEMM launch.
//   mode 0: q  = x @ Wq + bq      -> qh/qm f16 planes (3-pass split source)
//   mode 1: k  = slots @ Wk + bk  -> kh/km f16 planes (rows rowoff+..)
//   mode 2: v  = slots @ Wv + bv  -> v16 f16 plane    (rows rowoff+..)
//   mode 3: oproj = RW*(retr16 @ Wp + bp) -> f32 out  (prev batch)
// Tiles: [0,n_q) q | [n_q, n_q+n_kv) k | [.., n_q+2*n_kv) v | rest proj.
// Staging swizzle (verified r8): p(c,r) = c ^ (r&3) ^ ((r>>2)&1).
// ---------------------------------------------------------------------------
__global__ __launch_bounds__(256) void producers(
    const float* __restrict__ xq, const float* __restrict__ aslots,
    const f16* __restrict__ aproj,
    const float* __restrict__ WqT, const float* __restrict__ WkT,
    const float* __restrict__ WvT, const float* __restrict__ WpT,
    const float* __restrict__ bq, const float* __restrict__ bk,
    const float* __restrict__ bv, const float* __restrict__ bp,
    f16* __restrict__ qh, f16* __restrict__ qm,
    f16* __restrict__ kh, f16* __restrict__ km,
    f16* __restrict__ v16, float* __restrict__ oproj,
    int n_q, int n_kv, int rowoff)
{
    __shared__ f16 LAh[4096], LAm[4096], LBh[4096], LBm[4096];
    const int tid = threadIdx.x;
    const int lane = tid & 63;
    const int wc = (tid >> 6) & 1;
    const int wr = (tid >> 7) & 1;

    int t = blockIdx.x, mode, bx, by;
    if (t < n_q) { mode = 0; bx = t % 6; by = t / 6; }
    else if (t < n_q + n_kv) { mode = 1; int u = t - n_q; bx = u % 6; by = u / 6; }
    else if (t < n_q + 2 * n_kv) { mode = 2; int u = t - n_q - n_kv; bx = u % 6; by = u / 6; }
    else { mode = 3; int u = t - n_q - 2 * n_kv; bx = u % 6; by = u / 6; }

    const int srow = tid >> 1, c0 = tid & 1;
    const int p0 = c0 ^ (srow & 3) ^ ((srow >> 2) & 1);
    const int wo0 = srow * 32 + p0 * 8, wo1 = wo0 ^ 16;
    const int csw = (((lane >> 4) ^ (lane & 3) ^ ((lane >> 2) & 1)) * 8);
    const int arow0 = by * 128;
    const size_t bn = (size_t)bx * 128;

    f32x4 acc[4][4];
#pragma unroll
    for (int i = 0; i < 4; ++i)
#pragma unroll
        for (int j = 0; j < 4; ++j) acc[i][j] = (f32x4){0.f, 0.f, 0.f, 0.f};

    const int orow0 = wr * 64 + (lane >> 4) * 4;
    const int ocol0 = wc * 64 + (lane & 15);

    if (mode <= 1) {                       // ---- 3-pass split to planes ----
        const float* A  = (mode == 0) ? xq : aslots;
        const float* BT = (mode == 0) ? WqT : WkT;
        const float* bi = (mode == 0) ? bq : bk;
        f16* Ch = (mode == 0) ? qh : kh;
        f16* Cm = (mode == 0) ? qm : km;
        const int crow0 = ((mode == 0) ? 0 : rowoff) + arow0;
        const float* pa = A + (size_t)(arow0 + srow) * 768 + c0 * 8;
        const float* pb = BT + (bn + srow) * 768 + c0 * 8;

        for (int k0 = 0; k0 < 768; k0 += 32) {
            float4 a0 = *(const float4*)(pa + k0);
            float4 a1 = *(const float4*)(pa + k0 + 4);
            float4 a2 = *(const float4*)(pa + k0 + 16);
            float4 a3 = *(const float4*)(pa + k0 + 20);
            float4 b0 = *(const float4*)(pb + k0);
            float4 b1 = *(const float4*)(pb + k0 + 4);
            float4 b2 = *(const float4*)(pb + k0 + 16);
            float4 b3 = *(const float4*)(pb + k0 + 20);
            __syncthreads();
            {
                float av[16] = {a0.x, a0.y, a0.z, a0.w, a1.x, a1.y, a1.z, a1.w,
                                a2.x, a2.y, a2.z, a2.w, a3.x, a3.y, a3.z, a3.w};
                float bv2[16] = {b0.x, b0.y, b0.z, b0.w, b1.x, b1.y, b1.z, b1.w,
                                 b2.x, b2.y, b2.z, b2.w, b3.x, b3.y, b3.z, b3.w};
                f16x8 h, m;
#pragma unroll
                for (int j = 0; j < 8; ++j) {
                    f16 hh = (f16)av[j]; h[j] = hh; m[j] = (f16)(av[j] - (float)hh);
                }
                *(f16x8*)&LAh[wo0] = h; *(f16x8*)&LAm[wo0] = m;
#pragma unroll
                for (int j = 0; j < 8; ++j) {
                    f16 hh = (f16)av[j + 8]; h[j] = hh; m[j] = (f16)(av[j + 8] - (float)hh);
                }
                *(f16x8*)&LAh[wo1] = h; *(f16x8*)&LAm[wo1] = m;
#pragma unroll
                for (int j = 0; j < 8; ++j) {
                    f16 hh = (f16)bv2[j]; h[j] = hh; m[j] = (f16)(bv2[j] - (float)hh);
                }
                *(f16x8*)&LBh[wo0] = h; *(f16x8*)&LBm[wo0] = m;
#pragma unroll
                for (int j = 0; j < 8; ++j) {
                    f16 hh = (f16)bv2[j + 8]; h[j] = hh; m[j] = (f16)(bv2[j + 8] - (float)hh);
                }
                *(f16x8*)&LBh[wo1] = h; *(f16x8*)&LBm[wo1] = m;
            }
            __syncthreads();

            f16x8 fah[4], fam[4], fbh[4], fbm[4];
#pragma unroll
            for (int mi = 0; mi < 4; ++mi) {
                int off = (wr * 64 + mi * 16 + (lane & 15)) * 32 + csw;
                fah[mi] = *(const f16x8*)&LAh[off];
                fam[mi] = *(const f16x8*)&LAm[off];
            }
#pragma unroll
            for (int ni = 0; ni < 4; ++ni) {
                int off = (wc * 64 + ni * 16 + (lane & 15)) * 32 + csw;
                fbh[ni] = *(const f16x8*)&LBh[off];
                fbm[ni] = *(const f16x8*)&LBm[off];
            }
#pragma unroll
            for (int mi = 0; mi < 4; ++mi)
#pragma unroll
                for (int ni = 0; ni < 4; ++ni) {
                    acc[mi][ni] = __builtin_amdgcn_mfma_f32_16x16x32_f16(
                        fah[mi], fbh[ni], acc[mi][ni], 0, 0, 0);
                    acc[mi][ni] = __builtin_amdgcn_mfma_f32_16x16x32_f16(
                        fah[mi], fbm[ni], acc[mi][ni], 0, 0, 0);
                    acc[mi][ni] = __builtin_amdgcn_mfma_f32_16x16x32_f16(
                        fam[mi], fbh[ni], acc[mi][ni], 0, 0, 0);
                }
        }
#pragma unroll
        for (int mi = 0; mi < 4; ++mi)
#pragma unroll
            for (int ni = 0; ni < 4; ++ni) {
                size_t col = bn + ocol0 + ni * 16;
                float badd = bi[col];
                size_t rbase = (size_t)crow0 + orow0 + mi * 16;
#pragma unroll
                for (int r = 0; r < 4; ++r) {
                    float val = acc[mi][ni][r] + badd;
                    f16 h = (f16)val;
                    size_t idx = (rbase + r) * 768 + col;
                    Ch[idx] = h;
                    Cm[idx] = (f16)(val - (float)h);
                }
            }
    } else if (mode == 2) {                // ---- 1-pass f16: v plane ----
        const int crow0 = rowoff + arow0;
        const float* pa = aslots + (size_t)(arow0 + srow) * 768 + c0 * 8;
        const float* pb = WvT + (bn + srow) * 768 + c0 * 8;
        for (int k0 = 0; k0 < 768; k0 += 32) {
            float4 a0 = *(const float4*)(pa + k0);
            float4 a1 = *(const float4*)(pa + k0 + 4);
            float4 a2 = *(const float4*)(pa + k0 + 16);
            float4 a3 = *(const float4*)(pa + k0 + 20);
            float4 b0 = *(const float4*)(pb + k0);
            float4 b1 = *(const float4*)(pb + k0 + 4);
            float4 b2 = *(const float4*)(pb + k0 + 16);
            float4 b3 = *(const float4*)(pb + k0 + 20);
            __syncthreads();
            {
                f16x8 h;
                h[0] = (f16)a0.x; h[1] = (f16)a0.y; h[2] = (f16)a0.z; h[3] = (f16)a0.w;
                h[4] = (f16)a1.x; h[5] = (f16)a1.y; h[6] = (f16)a1.z; h[7] = (f16)a1.w;
                *(f16x8*)&LAh[wo0] = h;
                h[0] = (f16)a2.x; h[1] = (f16)a2.y; h[2] = (f16)a2.z; h[3] = (f16)a2.w;
                h[4] = (f16)a3.x; h[5] = (f16)a3.y; h[6] = (f16)a3.z; h[7] = (f16)a3.w;
                *(f16x8*)&LAh[wo1] = h;
                h[0] = (f16)b0.x; h[1] = (f16)b0.y; h[2] = (f16)b0.z; h[3] = (f16)b0.w;
                h[4] = (f16)b1.x; h[5] = (f16)b1.y; h[6] = (f16)b1.z; h[7] = (f16)b1.w;
                *(f16x8*)&LBh[wo0] = h;
                h[0] = (f16)b2.x; h[1] = (f16)b2.y; h[2] = (f16)b2.z; h[3] = (f16)b2.w;
                h[4] = (f16)b3.x; h[5] = (f16)b3.y; h[6] = (f16)b3.z; h[7] = (f16)b3.w;
                *(f16x8*)&LBh[wo1] = h;
            }
            __syncthreads();
            f16x8 fah[4], fbh[4];
#pragma unroll
            for (int mi = 0; mi < 4; ++mi)
                fah[mi] = *(const f16x8*)&LAh[(wr * 64 + mi * 16 + (lane & 15)) * 32 + csw];
#pragma unroll
            for (int ni = 0; ni < 4; ++ni)
                fbh[ni] = *(const f16x8*)&LBh[(wc * 64 + ni * 16 + (lane & 15)) * 32 + csw];
#pragma unroll
            for (int mi = 0; mi < 4; ++mi)
#pragma unroll
                for (int ni = 0; ni < 4; ++ni)
                    acc[mi][ni] = __builtin_amdgcn_mfma_f32_16x16x32_f16(
                        fah[mi], fbh[ni], acc[mi][ni], 0, 0, 0);
        }
#pragma unroll
        for (int mi = 0; mi < 4; ++mi)
#pragma unroll
            for (int ni = 0; ni < 4; ++ni) {
                size_t col = bn + ocol0 + ni * 16;
                float badd = bv[col];
                size_t rbase = (size_t)crow0 + orow0 + mi * 16;
#pragma unroll
                for (int r = 0; r < 4; ++r)
                    v16[(rbase + r) * 768 + col] = (f16)(acc[mi][ni][r] + badd);
            }
    } else {                               // ---- 1-pass: proj (A f16) ----
        const f16* pa = aproj + (size_t)(arow0 + srow) * 768 + c0 * 8;
        const float* pb = WpT + (bn + srow) * 768 + c0 * 8;
        for (int k0 = 0; k0 < 768; k0 += 32) {
            f16x8 ah0 = *(const f16x8*)(pa + k0);
            f16x8 ah1 = *(const f16x8*)(pa + k0 + 16);
            float4 b0 = *(const float4*)(pb + k0);
            float4 b1 = *(const float4*)(pb + k0 + 4);
            float4 b2 = *(const float4*)(pb + k0 + 16);
            float4 b3 = *(const float4*)(pb + k0 + 20);
            __syncthreads();
            *(f16x8*)&LAh[wo0] = ah0;
            *(f16x8*)&LAh[wo1] = ah1;
            {
                f16x8 h;
                h[0] = (f16)b0.x; h[1] = (f16)b0.y; h[2] = (f16)b0.z; h[3] = (f16)b0.w;
                h[4] = (f16)b1.x; h[5] = (f16)b1.y; h[6] = (f16)b1.z; h[7] = (f16)b1.w;
                *(f16x8*)&LBh[wo0] = h;
                h[0] = (f16)b2.x; h[1] = (f16)b2.y; h[2] = (f16)b2.z; h[3] = (f16)b2.w;
                h[4] = (f16)b3.x; h[5] = (f16)b3.y; h[6] = (f16)b3.z; h[7] = (f16)b3.w;
                *(f16x8*)&LBh[wo1] = h;
            }
            __syncthreads();
            f16x8 fah[4], fbh[4];
#pragma unroll
            for (int mi = 0; mi < 4; ++mi)
                fah[mi] = *(const f16x8*)&LAh[(wr * 64 + mi * 16 + (lane & 15)) * 32 + csw];
#pragma unroll
            for (int ni = 0; ni < 4; ++ni)
                fbh[ni] = *(const f16x8*)&LBh[(wc * 64 + ni * 16 + (lane & 15)) * 32 + csw];
#pragma unroll
            for (int mi = 0; mi < 4; ++mi)
#pragma unroll
                for (int ni = 0; ni < 4; ++ni)
                    acc[mi][ni] = __builtin_amdgcn_mfma_f32_16x16x32_f16(
                        fah[mi], fbh[ni], acc[mi][ni], 0, 0, 0);
        }
#pragma unroll
        for (int mi = 0; mi < 4; ++mi)
#pragma unroll
            for (int ni = 0; ni < 4; ++ni) {
                size_t col = bn + ocol0 + ni * 16;
                float badd = RWEIGHT * bp[col];
                size_t rbase = (size_t)arow0 + orow0 + mi * 16;
#pragma unroll
                for (int r = 0; r < 4; ++r)
                    oproj[(rbase + r) * 768 + col] = RWEIGHT * acc[mi][ni][r] + badd;
            }
    }
}

// ---------------------------------------------------------------------------
// scores_planes: C[M,2048] = alpha * (qh+qm)[M,768] @ (kh+km)[2048,768]^T
// 3-pass split MFMA; staging is pure 16B f16 copies (no conversion VALU).
// ---------------------------------------------------------------------------
__global__ __launch_bounds__(256) void scores_planes(
    const f16* __restrict__ qh, const f16* __restrict__ qm,
    const f16* __restrict__ kh, const f16* __restrict__ km,
    float* __restrict__ C, float alpha)
{
    __shared__ f16 LAh[4096], LAm[4096], LBh[4096], LBm[4096];
    const int tid = threadIdx.x;
    const int lane = tid & 63;
    const int wc = (tid >> 6) & 1;
    const int wr = (tid >> 7) & 1;
    const size_t bm = (size_t)blockIdx.y * 128;
    const size_t bn = (size_t)blockIdx.x * 128;

    f32x4 acc[4][4];
#pragma unroll
    for (int i = 0; i < 4; ++i)
#pragma unroll
        for (int j = 0; j < 4; ++j) acc[i][j] = (f32x4){0.f, 0.f, 0.f, 0.f};

    const int srow = tid >> 1, c0 = tid & 1;
    const int p0 = c0 ^ (srow & 3) ^ ((srow >> 2) & 1);
    const int wo0 = srow * 32 + p0 * 8, wo1 = wo0 ^ 16;
    const int csw = (((lane >> 4) ^ (lane & 3) ^ ((lane >> 2) & 1)) * 8);

    const f16* pah = qh + (bm + srow) * 768 + c0 * 8;
    const f16* pam = qm + (bm + srow) * 768 + c0 * 8;
    const f16* pbh = kh + (bn + srow) * 768 + c0 * 8;
    const f16* pbm = km + (bn + srow) * 768 + c0 * 8;

    for (int k0 = 0; k0 < 768; k0 += 32) {
        f16x8 ah0 = *(const f16x8*)(pah + k0);
        f16x8 ah1 = *(const f16x8*)(pah + k0 + 16);
        f16x8 am0 = *(const f16x8*)(pam + k0);
        f16x8 am1 = *(const f16x8*)(pam + k0 + 16);
        f16x8 bh0 = *(const f16x8*)(pbh + k0);
        f16x8 bh1 = *(const f16x8*)(pbh + k0 + 16);
        f16x8 bm0 = *(const f16x8*)(pbm + k0);
        f16x8 bm1 = *(const f16x8*)(pbm + k0 + 16);
        __syncthreads();
        *(f16x8*)&LAh[wo0] = ah0; *(f16x8*)&LAh[wo1] = ah1;
        *(f16x8*)&LAm[wo0] = am0; *(f16x8*)&LAm[wo1] = am1;
        *(f16x8*)&LBh[wo0] = bh0; *(f16x8*)&LBh[wo1] = bh1;
        *(f16x8*)&LBm[wo0] = bm0; *(f16x8*)&LBm[wo1] = bm1;
        __syncthreads();

        f16x8 fah[4], fam[4], fbh[4], fbm[4];
#pragma unroll
        for (int mi = 0; mi < 4; ++mi) {
            int off = (wr * 64 + mi * 16 + (lane & 15)) * 32 + csw;
            fah[mi] = *(const f16x8*)&LAh[off];
            fam[mi] = *(const f16x8*)&LAm[off];
        }
#pragma unroll
        for (int ni = 0; ni < 4; ++ni) {
            int off = (wc * 64 + ni * 16 + (lane & 15)) * 32 + csw;
            fbh[ni] = *(const f16x8*)&LBh[off];
            fbm[ni] = *(const f16x8*)&LBm[off];
        }
#pragma unroll
        for (int mi = 0; mi < 4; ++mi)
#pragma unroll
            for (int ni = 0; ni < 4; ++ni) {
                acc[mi][ni] = __builtin_amdgcn_mfma_f32_16x16x32_f16(
                    fah[mi], fbh[ni], acc[mi][ni], 0, 0, 0);
                acc[mi][ni] = __builtin_amdgcn_mfma_f32_16x16x32_f16(
                    fah[mi], fbm[ni], acc[mi][ni], 0, 0, 0);
                acc[mi][ni] = __builtin_amdgcn_mfma_f32_16x16x32_f16(
                    fam[mi], fbh[ni], acc[mi][ni], 0, 0, 0);
            }
    }

    const int orow0 = wr * 64 + (lane >> 4) * 4;
    const int ocol0 = wc * 64 + (lane & 15);
#pragma unroll
    for (int mi = 0; mi < 4; ++mi)
#pragma unroll
        for (int ni = 0; ni < 4; ++ni) {
            size_t col = bn + ocol0 + ni * 16;
            size_t rbase = bm + orow0 + mi * 16;
#pragma unroll
            for (int r = 0; r < 4; ++r)
                C[(rbase + r) * S2 + col] = alpha * acc[mi][ni][r];
        }
}

// ---------------------------------------------------------------------------
template <int NR>
__device__ void wave_topk(const float* __restrict__ srow, int lane,
                          float* topv, int* topi)
{
    float vals[32];
#pragma unroll
    for (int i = 0; i < 32; ++i) vals[i] = srow[lane + (i << 6)];
#pragma unroll
    for (int r = 0; r < NR; ++r) {
        float bvv = -3.4e38f; int bii = 0x7fffffff;
#pragma unroll
        for (int i = 0; i < 32; ++i)
            if (vals[i] > bvv) { bvv = vals[i]; bii = lane + (i << 6); }
#pragma unroll
        for (int off = 32; off > 0; off >>= 1) {
            float ov = __shfl_xor(bvv, off);
            int   oi = __shfl_xor(bii, off);
            if (ov > bvv || (ov == bvv && oi < bii)) { bvv = ov; bii = oi; }
        }
        topv[r] = bvv; topi[r] = bii;
        if ((bii & 63) == lane) vals[bii >> 6] = -3.4e38f;
    }
}

// ---------------------------------------------------------------------------
// select_combine: one wave per row; f16 v gather; writes f16 retr.
// ---------------------------------------------------------------------------
__global__ __launch_bounds__(256) void select_combine(
    const float* __restrict__ scores, const f16* __restrict__ v16,
    f16* __restrict__ retrc,
    int* __restrict__ amb_count, int* __restrict__ amb_rows,
    int* __restrict__ cand)
{
    const int lane = threadIdx.x & 63;
    const int wave = threadIdx.x >> 6;
    const int row = blockIdx.x * 4 + wave;

    const float* srow = scores + (size_t)row * S2;
    float vals[32];
#pragma unroll
    for (int i = 0; i < 32; ++i) vals[i] = srow[lane + (i << 6)];

    float topv[16]; int topi[16];
    bool amb = false;
    int nr = 9;
    for (int r = 0; r < 16; ++r) {
        if (r >= nr) break;
        float bvv = -3.4e38f; int bii = 0x7fffffff;
#pragma unroll
        for (int i = 0; i < 32; ++i)
            if (vals[i] > bvv) { bvv = vals[i]; bii = lane + (i << 6); }
#pragma unroll
        for (int off = 32; off > 0; off >>= 1) {
            float ov = __shfl_xor(bvv, off);
            int   oi = __shfl_xor(bii, off);
            if (ov > bvv || (ov == bvv && oi < bii)) { bvv = ov; bii = oi; }
        }
        topv[r] = bvv; topi[r] = bii;
        if ((bii & 63) == lane) vals[bii >> 6] = -3.4e38f;
        if (r == 8) {
            amb = (topv[7] - topv[8]) < TAU;
            if (amb) nr = 16;
        }
    }

    if (amb) {
        int idx = 0;
        if (lane == 0) idx = atomicAdd(amb_count, 1);
        idx = __shfl(idx, 0);
        if (idx < AMB_CAP) {
            if (lane == 0) amb_rows[idx] = row;
            if (lane < 16) cand[idx * 16 + lane] = topi[lane];
        }
    }

    float m = topv[0], w[KTOP], sum = 0.f;
#pragma unroll
    for (int r = 0; r < KTOP; ++r) { w[r] = expf(topv[r] - m); sum += w[r]; }
    float inv = 1.f / sum;
#pragma unroll
    for (int r = 0; r < KTOP; ++r) w[r] *= inv;

    for (int c = lane; c < 96; c += 64) {       // 96 chunks of 8 f16
        float o[8] = {0, 0, 0, 0, 0, 0, 0, 0};
#pragma unroll
        for (int r = 0; r < KTOP; ++r) {
            f16x8 vv = *(const f16x8*)&v16[(size_t)topi[r] * 768 + c * 8];
#pragma unroll
            for (int j = 0; j < 8; ++j) o[j] += w[r] * (float)vv[j];
        }
        f16x8 hx;
#pragma unroll
        for (int j = 0; j < 8; ++j) hx[j] = (f16)o[j];
        *(f16x8*)&retrc[(size_t)row * 768 + c * 8] = hx;
    }
}

// ---------------------------------------------------------------------------
// F1: q64[i][j] = f64(x_row . Wq[:,j]) + bq[j].  grid (12, AMB_CAP).
// ---------------------------------------------------------------------------
__global__ __launch_bounds__(256) void fixup_q(
    const int* __restrict__ amb_count, const int* __restrict__ amb_rows,
    const float* __restrict__ xc, const float* __restrict__ Wq,
    const float* __restrict__ bq, double* __restrict__ q64buf)
{
    int n = *amb_count; if (n > AMB_CAP) n = AMB_CAP;
    const int i = blockIdx.y;
    if (i >= n) return;
    const int tid = threadIdx.x;
    const int jl = tid & 63;
    const int ks = tid >> 6;
    const int j = blockIdx.x * 64 + jl;
    const int row = amb_rows[i];

    __shared__ float xs[768];
    __shared__ double ps[4][64];
    for (int t = tid; t < 768; t += 256) xs[t] = xc[(size_t)row * 768 + t];
    __syncthreads();

    double a0 = 0.0, a1 = 0.0;
    const float* wp = Wq + j;
    const int k0 = ks * 192;
#pragma unroll 8
    for (int k = 0; k < 192; k += 2) {
        a0 = fma((double)xs[k0 + k],     (double)wp[(size_t)(k0 + k) * 768],     a0);
        a1 = fma((double)xs[k0 + k + 1], (double)wp[(size_t)(k0 + k + 1) * 768], a1);
    }
    ps[ks][jl] = a0 + a1;
    __syncthreads();
    if (ks == 0)
        q64buf[(size_t)i * 768 + j] =
            ((ps[0][jl] + ps[1][jl]) + (ps[2][jl] + ps[3][jl])) + (double)bq[j];
}

// ---------------------------------------------------------------------------
// F2: u[i][t] = sum_j WkT[j][t] * q64[i][j].  grid (12, AMB_CAP).
// ---------------------------------------------------------------------------
__global__ __launch_bounds__(256) void fixup_u(
    const int* __restrict__ amb_count,
    const float* __restrict__ WkT, const float* __restrict__ bk,
    const double* __restrict__ q64buf,
    double* __restrict__ ubuf, double* __restrict__ bkqbuf)
{
    int n = *amb_count; if (n > AMB_CAP) n = AMB_CAP;
    const int i = blockIdx.y;
    if (i >= n) return;
    const int tid = threadIdx.x;
    const int tl = tid & 63;
    const int js = tid >> 6;
    const int t = blockIdx.x * 64 + tl;

    __shared__ double qs[768];
    __shared__ double ps[4][64];
    const double* qrow = q64buf + (size_t)i * 768;
    for (int k = tid; k < 768; k += 256) qs[k] = qrow[k];
    __syncthreads();

    double a0 = 0.0, a1 = 0.0;
    const float* wp = WkT + t;
    const int j0 = js * 192;
#pragma unroll 8
    for (int k = 0; k < 192; k += 2) {
        a0 = fma((double)wp[(size_t)(j0 + k) * 768],     qs[j0 + k],     a0);
        a1 = fma((double)wp[(size_t)(j0 + k + 1) * 768], qs[j0 + k + 1], a1);
    }
    ps[js][tl] = a0 + a1;
    __syncthreads();
    if (js == 0)
        ubuf[(size_t)i * 768 + t] = (ps[0][tl] + ps[1][tl]) + (ps[2][tl] + ps[3][tl]);

    if (blockIdx.x == 0 && tid < 64) {
        double p = 0.0;
#pragma unroll
        for (int c = 0; c < 12; ++c) {
            int jj = tid + (c << 6);
            p = fma((double)bk[jj], qs[jj], p);
        }
#pragma unroll
        for (int off = 32; off; off >>= 1) p += __shfl_xor(p, off);
        if (tid == 0) bkqbuf[i] = p;
    }
}

// ---------------------------------------------------------------------------
// F3: per amb row: 16 exact scores, f64 top-8, f64 softmax, f16 combine.
// ---------------------------------------------------------------------------
__global__ __launch_bounds__(256) void fixup_sel(
    const int* __restrict__ amb_count, const int* __restrict__ amb_rows,
    const float* __restrict__ xb, const float* __restrict__ pm,
    const int* __restrict__ cand, const double* __restrict__ ubuf,
    const double* __restrict__ bkqbuf, const f16* __restrict__ v16,
    f16* __restrict__ retrc)
{
    int n = *amb_count; if (n > AMB_CAP) n = AMB_CAP;
    const int i = blockIdx.x;
    if (i >= n) return;
    const int tid = threadIdx.x;
    const int lane = tid & 63;
    const int wave = tid >> 6;
    const int row = amb_rows[i];

    __shared__ double us[768];
    __shared__ double cs_s[16];
    __shared__ float wsm[KTOP];
    __shared__ int seli[KTOP];

    const double* urow = ubuf + (size_t)i * 768;
    for (int t = tid; t < 768; t += 256) us[t] = urow[t];
    __syncthreads();

    const double ISQ = 1.0 / sqrt((double)DD);
    const double bkq = bkqbuf[i];
#pragma unroll
    for (int c = wave; c < 16; c += 4) {
        int s = cand[i * 16 + c];
        double p = 0.0;
        if (s < SS) {
            const float* xr = xb + (size_t)(4 * s) * 768;
#pragma unroll
            for (int t = 0; t < 12; ++t) {
                int j2 = lane + (t << 6);
                double sv = 0.25 * ((double)xr[j2] + (double)xr[j2 + 768] +
                                    (double)xr[j2 + 1536] + (double)xr[j2 + 2304]);
                p = fma(sv, us[j2], p);
            }
        } else {
            const float* pr = pm + (size_t)(s - SS) * 768;
#pragma unroll
            for (int t = 0; t < 12; ++t) {
                int j2 = lane + (t << 6);
                p = fma((double)pr[j2], us[j2], p);
            }
        }
#pragma unroll
        for (int off = 32; off; off >>= 1) p += __shfl_xor(p, off);
        if (lane == 0) cs_s[c] = (p + bkq) * ISQ;
    }
    __syncthreads();

    if (tid == 0) {
        double cs[16]; int ci[16];
        for (int c = 0; c < 16; ++c) { cs[c] = cs_s[c]; ci[c] = cand[i * 16 + c]; }
        unsigned used = 0;
        double sv[KTOP]; int sx[KTOP];
        for (int r = 0; r < KTOP; ++r) {
            int bi = -1;
            for (int c = 0; c < 16; ++c) {
                if (used & (1u << c)) continue;
                if (bi < 0 || cs[c] > cs[bi] ||
                    (cs[c] == cs[bi] && ci[c] < ci[bi])) bi = c;
            }
            used |= (1u << bi); sv[r] = cs[bi]; sx[r] = ci[bi];
        }
        double mx = sv[0], es[KTOP], ssum = 0.0;
        for (int r = 0; r < KTOP; ++r) { es[r] = exp(sv[r] - mx); ssum += es[r]; }
        for (int r = 0; r < KTOP; ++r) { wsm[r] = (float)(es[r] / ssum); seli[r] = sx[r]; }
    }
    __syncthreads();
    for (int c = tid; c < 96; c += 256) {
        float o[8] = {0, 0, 0, 0, 0, 0, 0, 0};
#pragma unroll
        for (int r = 0; r < KTOP; ++r) {
            f16x8 vv = *(const f16x8*)&v16[(size_t)seli[r] * 768 + c * 8];
#pragma unroll
            for (int j = 0; j < 8; ++j) o[j] += wsm[r] * (float)vv[j];
        }
        f16x8 hx;
#pragma unroll
        for (int j = 0; j < 8; ++j) hx[j] = (f16)o[j];
        *(f16x8*)&retrc[(size_t)row * 768 + c * 8] = hx;
    }
}

// ---------------------------------------------------------------------------
extern "C" void kernel_launch(void* const* d_in, const int* in_sizes, int n_in,
                              void* d_out, int out_size, void* d_ws, size_t ws_size,
                              hipStream_t stream)
{
    const float* x  = (const float*)d_in[0];
    const float* Wq = (const float*)d_in[1];
    const float* bq = (const float*)d_in[2];
    const float* Wk = (const float*)d_in[3];
    const float* bk = (const float*)d_in[4];
    const float* Wv = (const float*)d_in[5];
    const float* bv = (const float*)d_in[6];
    const float* Wp = (const float*)d_in[7];
    const float* bp = (const float*)d_in[8];
    const float* pm = (const float*)d_in[9];
    float* out = (float*)d_out;
    float* ws  = (float*)d_ws;

    const float inv_sqrt_d = (float)(1.0 / sqrt((double)DD));
    const size_t TD  = (size_t)TT * DD;
    const size_t SD  = (size_t)SS * DD;
    const size_t WSZ = (size_t)DD * DD;

    float* p = ws;
    float* WqT = p; p += WSZ;
    float* WkT = p; p += WSZ;
    float* WvT = p; p += WSZ;
    float* WpT = p; p += WSZ;
    float* slots_all = p; p += (size_t)BB * SD;
    f16* qh = (f16*)p; p += TD / 2;
    f16* qm = (f16*)p; p += TD / 2;
    f16* kh = (f16*)p; p += SD;            // [2S][768] f16 = SD float units
    f16* km = (f16*)p; p += SD;
    f16* v16 = (f16*)p; p += SD;
    f16* retrA = (f16*)p; p += TD / 2;
    f16* retrB = (f16*)p; p += TD / 2;
    double* q64buf = (double*)p; p += (size_t)AMB_CAP * DD * 2;
    double* ubuf   = (double*)p; p += (size_t)AMB_CAP * DD * 2;
    double* bkqbuf = (double*)p; p += AMB_CAP * 2;
    int* cand = (int*)p; p += (size_t)AMB_CAP * 16;
    int* ambc = (int*)p; p += 64;
    int* ambrows = (int*)p; p += AMB_CAP;
    float* scores = p;
    size_t used = (size_t)(p - ws);

    long tc = TT;
    while (tc > 512 && (used + (size_t)tc * S2) * 4 > ws_size) tc >>= 1;

    transpose_all<<<dim3(24, 24, 4), 256, 0, stream>>>(
        Wq, Wk, Wv, Wp, WqT, WkT, WvT, WpT);
    zeroN<<<1, 64, 0, stream>>>(ambc);
    build_pooled_all<<<(BB * SS * DD) / 256, 256, 0, stream>>>(x, slots_all);

    // prolog: pm halves of k/v planes (rows S..2S-1), once.
    producers<<<96, 256, 0, stream>>>(
        nullptr, pm, nullptr, WqT, WkT, WvT, WpT, bq, bk, bv, bp,
        qh, qm, kh, km, v16, nullptr, 0, 48, SS);

    int cidx = 0;
    for (int b = 0; b < BB; ++b) {
        const float* xb = x + (size_t)b * TD;
        const float* slots_b = slots_all + (size_t)b * SD;
        f16* rcur = (b & 1) ? retrB : retrA;
        f16* rprev = (b & 1) ? retrA : retrB;
        int np = b ? 192 : 0;

        producers<<<288 + np, 256, 0, stream>>>(
            xb, slots_b, rprev, WqT, WkT, WvT, WpT, bq, bk, bv, bp,
            qh, qm, kh, km, v16, out + (size_t)(b - 1) * TD, 192, 48, 0);

        for (long t0 = 0; t0 < TT; t0 += tc) {
            int* cc = ambc + cidx; cidx = (cidx + 1) & 63;
            scores_planes<<<dim3(16, tc / 128), 256, 0, stream>>>(
                qh + (size_t)t0 * DD, qm + (size_t)t0 * DD, kh, km,
                scores, inv_sqrt_d);
            select_combine<<<tc / 4, 256, 0, stream>>>(
                scores, v16, rcur + (size_t)t0 * DD, cc, ambrows, cand);
            fixup_q<<<dim3(12, AMB_CAP), 256, 0, stream>>>(
                cc, ambrows, xb + (size_t)t0 * DD, Wq, bq, q64buf);
            fixup_u<<<dim3(12, AMB_CAP), 256, 0, stream>>>(
                cc, WkT, bk, q64buf, ubuf, bkqbuf);
            fixup_sel<<<AMB_CAP, 256, 0, stream>>>(
                cc, ambrows, xb, pm, cand, ubuf, bkqbuf, v16,
                rcur + (size_t)t0 * DD);
        }
    }

    // tail: proj of last batch.
    f16* rlast = ((BB - 1) & 1) ? retrB : retrA;
    producers<<<192, 256, 0, stream>>>(
        nullptr, nullptr, rlast, WqT, WkT, WvT, WpT, bq, bk, bv, bp,
        qh, qm, kh, km, v16, out + (size_t)(BB - 1) * TD, 0, 0, 0);
}

// Round 10
// 648.535 us; speedup vs baseline: 1.7592x; 1.0888x over previous
//
#include <hip/hip_runtime.h>
#include <math.h>

#define BB 4
#define TT 4096
#define DD 768
#define SS 1024
#define S2 2048
#define KTOP 8
#define RWEIGHT 0.1f
#define TAU 2e-4f
#define AMB_CAP 128

typedef __attribute__((ext_vector_type(8))) _Float16 f16x8;
typedef __attribute__((ext_vector_type(4))) float f32x4;
typedef _Float16 f16;

// ---------------------------------------------------------------------------
__global__ __launch_bounds__(256) void build_pooled_all(
    const float* __restrict__ x, float* __restrict__ slots)
{
    int i = blockIdx.x * 256 + threadIdx.x;     // over B*S*D = 3145728
    int s2 = i / DD;
    int d = i - s2 * DD;
    int b = s2 >> 10, s = s2 & 1023;
    const float* xb = x + (size_t)b * TT * DD + (size_t)(4 * s) * DD + d;
    slots[i] = 0.25f * (xb[0] + xb[DD] + xb[2 * DD] + xb[3 * DD]);
}

// ---------------------------------------------------------------------------
__global__ __launch_bounds__(256) void transpose_all(
    const float* __restrict__ W0, const float* __restrict__ W1,
    const float* __restrict__ W2, const float* __restrict__ W3,
    float* __restrict__ T0, float* __restrict__ T1,
    float* __restrict__ T2, float* __restrict__ T3)
{
    const float* W = (blockIdx.z == 0) ? W0 : (blockIdx.z == 1) ? W1
                   : (blockIdx.z == 2) ? W2 : W3;
    float* WT = (blockIdx.z == 0) ? T0 : (blockIdx.z == 1) ? T1
              : (blockIdx.z == 2) ? T2 : T3;
    __shared__ float t[32][33];
    int bx = blockIdx.x * 32, by = blockIdx.y * 32;
    int lx = threadIdx.x & 31, ly = threadIdx.x >> 5;
#pragma unroll
    for (int r = 0; r < 32; r += 8)
        t[ly + r][lx] = W[(size_t)(bx + ly + r) * 768 + by + lx];
    __syncthreads();
#pragma unroll
    for (int r = 0; r < 32; r += 8)
        WT[(size_t)(by + ly + r) * 768 + bx + lx] = t[lx][ly + r];
}

__global__ void zeroN(int* p) { p[threadIdx.x] = 0; }

// ---------------------------------------------------------------------------
// producers: merged per-batch GEMM launch (q split-planes | k split-planes |
// v f16 | proj of previous batch). Staging swizzle verified r8.
// ---------------------------------------------------------------------------
__global__ __launch_bounds__(256) void producers(
    const float* __restrict__ xq, const float* __restrict__ aslots,
    const f16* __restrict__ aproj,
    const float* __restrict__ WqT, const float* __restrict__ WkT,
    const float* __restrict__ WvT, const float* __restrict__ WpT,
    const float* __restrict__ bq, const float* __restrict__ bk,
    const float* __restrict__ bv, const float* __restrict__ bp,
    f16* __restrict__ qh, f16* __restrict__ qm,
    f16* __restrict__ kh, f16* __restrict__ km,
    f16* __restrict__ v16, float* __restrict__ oproj,
    int n_q, int n_kv, int rowoff)
{
    __shared__ f16 LAh[4096], LAm[4096], LBh[4096], LBm[4096];
    const int tid = threadIdx.x;
    const int lane = tid & 63;
    const int wc = (tid >> 6) & 1;
    const int wr = (tid >> 7) & 1;

    int t = blockIdx.x, mode, bx, by;
    if (t < n_q) { mode = 0; bx = t % 6; by = t / 6; }
    else if (t < n_q + n_kv) { mode = 1; int u = t - n_q; bx = u % 6; by = u / 6; }
    else if (t < n_q + 2 * n_kv) { mode = 2; int u = t - n_q - n_kv; bx = u % 6; by = u / 6; }
    else { mode = 3; int u = t - n_q - 2 * n_kv; bx = u % 6; by = u / 6; }

    const int srow = tid >> 1, c0 = tid & 1;
    const int p0 = c0 ^ (srow & 3) ^ ((srow >> 2) & 1);
    const int wo0 = srow * 32 + p0 * 8, wo1 = wo0 ^ 16;
    const int csw = (((lane >> 4) ^ (lane & 3) ^ ((lane >> 2) & 1)) * 8);
    const int arow0 = by * 128;
    const size_t bn = (size_t)bx * 128;

    f32x4 acc[4][4];
#pragma unroll
    for (int i = 0; i < 4; ++i)
#pragma unroll
        for (int j = 0; j < 4; ++j) acc[i][j] = (f32x4){0.f, 0.f, 0.f, 0.f};

    const int orow0 = wr * 64 + (lane >> 4) * 4;
    const int ocol0 = wc * 64 + (lane & 15);

    if (mode <= 1) {
        const float* A  = (mode == 0) ? xq : aslots;
        const float* BT = (mode == 0) ? WqT : WkT;
        const float* bi = (mode == 0) ? bq : bk;
        f16* Ch = (mode == 0) ? qh : kh;
        f16* Cm = (mode == 0) ? qm : km;
        const int crow0 = ((mode == 0) ? 0 : rowoff) + arow0;
        const float* pa = A + (size_t)(arow0 + srow) * 768 + c0 * 8;
        const float* pb = BT + (bn + srow) * 768 + c0 * 8;

        for (int k0 = 0; k0 < 768; k0 += 32) {
            float4 a0 = *(const float4*)(pa + k0);
            float4 a1 = *(const float4*)(pa + k0 + 4);
            float4 a2 = *(const float4*)(pa + k0 + 16);
            float4 a3 = *(const float4*)(pa + k0 + 20);
            float4 b0 = *(const float4*)(pb + k0);
            float4 b1 = *(const float4*)(pb + k0 + 4);
            float4 b2 = *(const float4*)(pb + k0 + 16);
            float4 b3 = *(const float4*)(pb + k0 + 20);
            __syncthreads();
            {
                float av[16] = {a0.x, a0.y, a0.z, a0.w, a1.x, a1.y, a1.z, a1.w,
                                a2.x, a2.y, a2.z, a2.w, a3.x, a3.y, a3.z, a3.w};
                float bv2[16] = {b0.x, b0.y, b0.z, b0.w, b1.x, b1.y, b1.z, b1.w,
                                 b2.x, b2.y, b2.z, b2.w, b3.x, b3.y, b3.z, b3.w};
                f16x8 h, m;
#pragma unroll
                for (int j = 0; j < 8; ++j) {
                    f16 hh = (f16)av[j]; h[j] = hh; m[j] = (f16)(av[j] - (float)hh);
                }
                *(f16x8*)&LAh[wo0] = h; *(f16x8*)&LAm[wo0] = m;
#pragma unroll
                for (int j = 0; j < 8; ++j) {
                    f16 hh = (f16)av[j + 8]; h[j] = hh; m[j] = (f16)(av[j + 8] - (float)hh);
                }
                *(f16x8*)&LAh[wo1] = h; *(f16x8*)&LAm[wo1] = m;
#pragma unroll
                for (int j = 0; j < 8; ++j) {
                    f16 hh = (f16)bv2[j]; h[j] = hh; m[j] = (f16)(bv2[j] - (float)hh);
                }
                *(f16x8*)&LBh[wo0] = h; *(f16x8*)&LBm[wo0] = m;
#pragma unroll
                for (int j = 0; j < 8; ++j) {
                    f16 hh = (f16)bv2[j + 8]; h[j] = hh; m[j] = (f16)(bv2[j + 8] - (float)hh);
                }
                *(f16x8*)&LBh[wo1] = h; *(f16x8*)&LBm[wo1] = m;
            }
            __syncthreads();

            f16x8 fah[4], fam[4], fbh[4], fbm[4];
#pragma unroll
            for (int mi = 0; mi < 4; ++mi) {
                int off = (wr * 64 + mi * 16 + (lane & 15)) * 32 + csw;
                fah[mi] = *(const f16x8*)&LAh[off];
                fam[mi] = *(const f16x8*)&LAm[off];
            }
#pragma unroll
            for (int ni = 0; ni < 4; ++ni) {
                int off = (wc * 64 + ni * 16 + (lane & 15)) * 32 + csw;
                fbh[ni] = *(const f16x8*)&LBh[off];
                fbm[ni] = *(const f16x8*)&LBm[off];
            }
#pragma unroll
            for (int mi = 0; mi < 4; ++mi)
#pragma unroll
                for (int ni = 0; ni < 4; ++ni) {
                    acc[mi][ni] = __builtin_amdgcn_mfma_f32_16x16x32_f16(
                        fah[mi], fbh[ni], acc[mi][ni], 0, 0, 0);
                    acc[mi][ni] = __builtin_amdgcn_mfma_f32_16x16x32_f16(
                        fah[mi], fbm[ni], acc[mi][ni], 0, 0, 0);
                    acc[mi][ni] = __builtin_amdgcn_mfma_f32_16x16x32_f16(
                        fam[mi], fbh[ni], acc[mi][ni], 0, 0, 0);
                }
        }
#pragma unroll
        for (int mi = 0; mi < 4; ++mi)
#pragma unroll
            for (int ni = 0; ni < 4; ++ni) {
                size_t col = bn + ocol0 + ni * 16;
                float badd = bi[col];
                size_t rbase = (size_t)crow0 + orow0 + mi * 16;
#pragma unroll
                for (int r = 0; r < 4; ++r) {
                    float val = acc[mi][ni][r] + badd;
                    f16 h = (f16)val;
                    size_t idx = (rbase + r) * 768 + col;
                    Ch[idx] = h;
                    Cm[idx] = (f16)(val - (float)h);
                }
            }
    } else if (mode == 2) {
        const int crow0 = rowoff + arow0;
        const float* pa = aslots + (size_t)(arow0 + srow) * 768 + c0 * 8;
        const float* pb = WvT + (bn + srow) * 768 + c0 * 8;
        for (int k0 = 0; k0 < 768; k0 += 32) {
            float4 a0 = *(const float4*)(pa + k0);
            float4 a1 = *(const float4*)(pa + k0 + 4);
            float4 a2 = *(const float4*)(pa + k0 + 16);
            float4 a3 = *(const float4*)(pa + k0 + 20);
            float4 b0 = *(const float4*)(pb + k0);
            float4 b1 = *(const float4*)(pb + k0 + 4);
            float4 b2 = *(const float4*)(pb + k0 + 16);
            float4 b3 = *(const float4*)(pb + k0 + 20);
            __syncthreads();
            {
                f16x8 h;
                h[0] = (f16)a0.x; h[1] = (f16)a0.y; h[2] = (f16)a0.z; h[3] = (f16)a0.w;
                h[4] = (f16)a1.x; h[5] = (f16)a1.y; h[6] = (f16)a1.z; h[7] = (f16)a1.w;
                *(f16x8*)&LAh[wo0] = h;
                h[0] = (f16)a2.x; h[1] = (f16)a2.y; h[2] = (f16)a2.z; h[3] = (f16)a2.w;
                h[4] = (f16)a3.x; h[5] = (f16)a3.y; h[6] = (f16)a3.z; h[7] = (f16)a3.w;
                *(f16x8*)&LAh[wo1] = h;
                h[0] = (f16)b0.x; h[1] = (f16)b0.y; h[2] = (f16)b0.z; h[3] = (f16)b0.w;
                h[4] = (f16)b1.x; h[5] = (f16)b1.y; h[6] = (f16)b1.z; h[7] = (f16)b1.w;
                *(f16x8*)&LBh[wo0] = h;
                h[0] = (f16)b2.x; h[1] = (f16)b2.y; h[2] = (f16)b2.z; h[3] = (f16)b2.w;
                h[4] = (f16)b3.x; h[5] = (f16)b3.y; h[6] = (f16)b3.z; h[7] = (f16)b3.w;
                *(f16x8*)&LBh[wo1] = h;
            }
            __syncthreads();
            f16x8 fah[4], fbh[4];
#pragma unroll
            for (int mi = 0; mi < 4; ++mi)
                fah[mi] = *(const f16x8*)&LAh[(wr * 64 + mi * 16 + (lane & 15)) * 32 + csw];
#pragma unroll
            for (int ni = 0; ni < 4; ++ni)
                fbh[ni] = *(const f16x8*)&LBh[(wc * 64 + ni * 16 + (lane & 15)) * 32 + csw];
#pragma unroll
            for (int mi = 0; mi < 4; ++mi)
#pragma unroll
                for (int ni = 0; ni < 4; ++ni)
                    acc[mi][ni] = __builtin_amdgcn_mfma_f32_16x16x32_f16(
                        fah[mi], fbh[ni], acc[mi][ni], 0, 0, 0);
        }
#pragma unroll
        for (int mi = 0; mi < 4; ++mi)
#pragma unroll
            for (int ni = 0; ni < 4; ++ni) {
                size_t col = bn + ocol0 + ni * 16;
                float badd = bv[col];
                size_t rbase = (size_t)crow0 + orow0 + mi * 16;
#pragma unroll
                for (int r = 0; r < 4; ++r)
                    v16[(rbase + r) * 768 + col] = (f16)(acc[mi][ni][r] + badd);
            }
    } else {
        const f16* pa = aproj + (size_t)(arow0 + srow) * 768 + c0 * 8;
        const float* pb = WpT + (bn + srow) * 768 + c0 * 8;
        for (int k0 = 0; k0 < 768; k0 += 32) {
            f16x8 ah0 = *(const f16x8*)(pa + k0);
            f16x8 ah1 = *(const f16x8*)(pa + k0 + 16);
            float4 b0 = *(const float4*)(pb + k0);
            float4 b1 = *(const float4*)(pb + k0 + 4);
            float4 b2 = *(const float4*)(pb + k0 + 16);
            float4 b3 = *(const float4*)(pb + k0 + 20);
            __syncthreads();
            *(f16x8*)&LAh[wo0] = ah0;
            *(f16x8*)&LAh[wo1] = ah1;
            {
                f16x8 h;
                h[0] = (f16)b0.x; h[1] = (f16)b0.y; h[2] = (f16)b0.z; h[3] = (f16)b0.w;
                h[4] = (f16)b1.x; h[5] = (f16)b1.y; h[6] = (f16)b1.z; h[7] = (f16)b1.w;
                *(f16x8*)&LBh[wo0] = h;
                h[0] = (f16)b2.x; h[1] = (f16)b2.y; h[2] = (f16)b2.z; h[3] = (f16)b2.w;
                h[4] = (f16)b3.x; h[5] = (f16)b3.y; h[6] = (f16)b3.z; h[7] = (f16)b3.w;
                *(f16x8*)&LBh[wo1] = h;
            }
            __syncthreads();
            f16x8 fah[4], fbh[4];
#pragma unroll
            for (int mi = 0; mi < 4; ++mi)
                fah[mi] = *(const f16x8*)&LAh[(wr * 64 + mi * 16 + (lane & 15)) * 32 + csw];
#pragma unroll
            for (int ni = 0; ni < 4; ++ni)
                fbh[ni] = *(const f16x8*)&LBh[(wc * 64 + ni * 16 + (lane & 15)) * 32 + csw];
#pragma unroll
            for (int mi = 0; mi < 4; ++mi)
#pragma unroll
                for (int ni = 0; ni < 4; ++ni)
                    acc[mi][ni] = __builtin_amdgcn_mfma_f32_16x16x32_f16(
                        fah[mi], fbh[ni], acc[mi][ni], 0, 0, 0);
        }
#pragma unroll
        for (int mi = 0; mi < 4; ++mi)
#pragma unroll
            for (int ni = 0; ni < 4; ++ni) {
                size_t col = bn + ocol0 + ni * 16;
                float badd = RWEIGHT * bp[col];
                size_t rbase = (size_t)arow0 + orow0 + mi * 16;
#pragma unroll
                for (int r = 0; r < 4; ++r)
                    oproj[(rbase + r) * 768 + col] = RWEIGHT * acc[mi][ni][r] + badd;
            }
    }
}

// ---------------------------------------------------------------------------
// scores_planes: C = alpha * (qh+qm) @ (kh+km)^T  (3-pass, pure-copy staging)
// ---------------------------------------------------------------------------
__global__ __launch_bounds__(256) void scores_planes(
    const f16* __restrict__ qh, const f16* __restrict__ qm,
    const f16* __restrict__ kh, const f16* __restrict__ km,
    float* __restrict__ C, float alpha)
{
    __shared__ f16 LAh[4096], LAm[4096], LBh[4096], LBm[4096];
    const int tid = threadIdx.x;
    const int lane = tid & 63;
    const int wc = (tid >> 6) & 1;
    const int wr = (tid >> 7) & 1;
    const size_t bm = (size_t)blockIdx.y * 128;
    const size_t bn = (size_t)blockIdx.x * 128;

    f32x4 acc[4][4];
#pragma unroll
    for (int i = 0; i < 4; ++i)
#pragma unroll
        for (int j = 0; j < 4; ++j) acc[i][j] = (f32x4){0.f, 0.f, 0.f, 0.f};

    const int srow = tid >> 1, c0 = tid & 1;
    const int p0 = c0 ^ (srow & 3) ^ ((srow >> 2) & 1);
    const int wo0 = srow * 32 + p0 * 8, wo1 = wo0 ^ 16;
    const int csw = (((lane >> 4) ^ (lane & 3) ^ ((lane >> 2) & 1)) * 8);

    const f16* pah = qh + (bm + srow) * 768 + c0 * 8;
    const f16* pam = qm + (bm + srow) * 768 + c0 * 8;
    const f16* pbh = kh + (bn + srow) * 768 + c0 * 8;
    const f16* pbm = km + (bn + srow) * 768 + c0 * 8;

    for (int k0 = 0; k0 < 768; k0 += 32) {
        f16x8 ah0 = *(const f16x8*)(pah + k0);
        f16x8 ah1 = *(const f16x8*)(pah + k0 + 16);
        f16x8 am0 = *(const f16x8*)(pam + k0);
        f16x8 am1 = *(const f16x8*)(pam + k0 + 16);
        f16x8 bh0 = *(const f16x8*)(pbh + k0);
        f16x8 bh1 = *(const f16x8*)(pbh + k0 + 16);
        f16x8 bm0 = *(const f16x8*)(pbm + k0);
        f16x8 bm1 = *(const f16x8*)(pbm + k0 + 16);
        __syncthreads();
        *(f16x8*)&LAh[wo0] = ah0; *(f16x8*)&LAh[wo1] = ah1;
        *(f16x8*)&LAm[wo0] = am0; *(f16x8*)&LAm[wo1] = am1;
        *(f16x8*)&LBh[wo0] = bh0; *(f16x8*)&LBh[wo1] = bh1;
        *(f16x8*)&LBm[wo0] = bm0; *(f16x8*)&LBm[wo1] = bm1;
        __syncthreads();

        f16x8 fah[4], fam[4], fbh[4], fbm[4];
#pragma unroll
        for (int mi = 0; mi < 4; ++mi) {
            int off = (wr * 64 + mi * 16 + (lane & 15)) * 32 + csw;
            fah[mi] = *(const f16x8*)&LAh[off];
            fam[mi] = *(const f16x8*)&LAm[off];
        }
#pragma unroll
        for (int ni = 0; ni < 4; ++ni) {
            int off = (wc * 64 + ni * 16 + (lane & 15)) * 32 + csw;
            fbh[ni] = *(const f16x8*)&LBh[off];
            fbm[ni] = *(const f16x8*)&LBm[off];
        }
#pragma unroll
        for (int mi = 0; mi < 4; ++mi)
#pragma unroll
            for (int ni = 0; ni < 4; ++ni) {
                acc[mi][ni] = __builtin_amdgcn_mfma_f32_16x16x32_f16(
                    fah[mi], fbh[ni], acc[mi][ni], 0, 0, 0);
                acc[mi][ni] = __builtin_amdgcn_mfma_f32_16x16x32_f16(
                    fah[mi], fbm[ni], acc[mi][ni], 0, 0, 0);
                acc[mi][ni] = __builtin_amdgcn_mfma_f32_16x16x32_f16(
                    fam[mi], fbh[ni], acc[mi][ni], 0, 0, 0);
            }
    }

    const int orow0 = wr * 64 + (lane >> 4) * 4;
    const int ocol0 = wc * 64 + (lane & 15);
#pragma unroll
    for (int mi = 0; mi < 4; ++mi)
#pragma unroll
        for (int ni = 0; ni < 4; ++ni) {
            size_t col = bn + ocol0 + ni * 16;
            size_t rbase = bm + orow0 + mi * 16;
#pragma unroll
            for (int r = 0; r < 4; ++r)
                C[(rbase + r) * S2 + col] = alpha * acc[mi][ni][r];
        }
}

// ---------------------------------------------------------------------------
// select_combine: one wave per row; top-9 (ext 16 iff ambiguous); gap test;
// ambiguous rows store candidates + old weights + v16 snapshot (deferred fix).
// ---------------------------------------------------------------------------
__global__ __launch_bounds__(256) void select_combine(
    const float* __restrict__ scores, const f16* __restrict__ v16,
    f16* __restrict__ retrc, int gbase,
    int* __restrict__ amb_count, int* __restrict__ amb_grow,
    int* __restrict__ cand, float* __restrict__ oldw, f16* __restrict__ vsave)
{
    const int lane = threadIdx.x & 63;
    const int wave = threadIdx.x >> 6;
    const int row = blockIdx.x * 4 + wave;

    const float* srow = scores + (size_t)row * S2;
    float vals[32];
#pragma unroll
    for (int i = 0; i < 32; ++i) vals[i] = srow[lane + (i << 6)];

    float topv[16]; int topi[16];
    bool amb = false;
    int nr = 9;
    for (int r = 0; r < 16; ++r) {
        if (r >= nr) break;
        float bvv = -3.4e38f; int bii = 0x7fffffff;
#pragma unroll
        for (int i = 0; i < 32; ++i)
            if (vals[i] > bvv) { bvv = vals[i]; bii = lane + (i << 6); }
#pragma unroll
        for (int off = 32; off > 0; off >>= 1) {
            float ov = __shfl_xor(bvv, off);
            int   oi = __shfl_xor(bii, off);
            if (ov > bvv || (ov == bvv && oi < bii)) { bvv = ov; bii = oi; }
        }
        topv[r] = bvv; topi[r] = bii;
        if ((bii & 63) == lane) vals[bii >> 6] = -3.4e38f;
        if (r == 8) {
            amb = (topv[7] - topv[8]) < TAU;
            if (amb) nr = 16;
        }
    }

    float m = topv[0], w[KTOP], sum = 0.f;
#pragma unroll
    for (int r = 0; r < KTOP; ++r) { w[r] = expf(topv[r] - m); sum += w[r]; }
    float inv = 1.f / sum;
#pragma unroll
    for (int r = 0; r < KTOP; ++r) w[r] *= inv;

    if (amb) {
        int idx = 0;
        if (lane == 0) idx = atomicAdd(amb_count, 1);
        idx = __shfl(idx, 0);
        if (idx < AMB_CAP) {
            if (lane == 0) amb_grow[idx] = gbase + row;
            if (lane < 16) cand[idx * 16 + lane] = topi[lane];
            if (lane < KTOP) oldw[idx * KTOP + lane] = w[lane];
            // snapshot candidate v rows: 16 x 96 chunks of f16x8
            f16* vs = vsave + (size_t)idx * 16 * 768;
            for (int cc = lane; cc < 16 * 96; cc += 64) {
                int cr = cc / 96, ch = cc - cr * 96;
                *(f16x8*)&vs[(size_t)cr * 768 + ch * 8] =
                    *(const f16x8*)&v16[(size_t)topi[cr] * 768 + ch * 8];
            }
        }
    }

    for (int c = lane; c < 96; c += 64) {
        float o[8] = {0, 0, 0, 0, 0, 0, 0, 0};
#pragma unroll
        for (int r = 0; r < KTOP; ++r) {
            f16x8 vv = *(const f16x8*)&v16[(size_t)topi[r] * 768 + c * 8];
#pragma unroll
            for (int j = 0; j < 8; ++j) o[j] += w[r] * (float)vv[j];
        }
        f16x8 hx;
#pragma unroll
        for (int j = 0; j < 8; ++j) hx[j] = (f16)o[j];
        *(f16x8*)&retrc[(size_t)row * 768 + c * 8] = hx;
    }
}

// ---------------------------------------------------------------------------
// Deferred fixups (post-loop, all batches).
// fixA: q64[i][j] = f64(x[grow] . Wq[:,j]) + bq[j].  grid (12, AMB_CAP).
// ---------------------------------------------------------------------------
__global__ __launch_bounds__(256) void fixA(
    const int* __restrict__ amb_count, const int* __restrict__ amb_grow,
    const float* __restrict__ x, const float* __restrict__ Wq,
    const float* __restrict__ bq, double* __restrict__ q64buf)
{
    int n = *amb_count; if (n > AMB_CAP) n = AMB_CAP;
    const int i = blockIdx.y;
    if (i >= n) return;
    const int tid = threadIdx.x;
    const int jl = tid & 63;
    const int ks = tid >> 6;
    const int j = blockIdx.x * 64 + jl;
    const int grow = amb_grow[i];

    __shared__ float xs[768];
    __shared__ double ps[4][64];
    for (int t = tid; t < 768; t += 256) xs[t] = x[(size_t)grow * 768 + t];
    __syncthreads();

    double a0 = 0.0, a1 = 0.0;
    const float* wp = Wq + j;
    const int k0 = ks * 192;
#pragma unroll 8
    for (int k = 0; k < 192; k += 2) {
        a0 = fma((double)xs[k0 + k],     (double)wp[(size_t)(k0 + k) * 768],     a0);
        a1 = fma((double)xs[k0 + k + 1], (double)wp[(size_t)(k0 + k + 1) * 768], a1);
    }
    ps[ks][jl] = a0 + a1;
    __syncthreads();
    if (ks == 0)
        q64buf[(size_t)i * 768 + j] =
            ((ps[0][jl] + ps[1][jl]) + (ps[2][jl] + ps[3][jl])) + (double)bq[j];
}

// ---------------------------------------------------------------------------
// fixB: u[i][t] = Wk[t][:] . q64[i]; bkq.  grid (12, AMB_CAP).
// ---------------------------------------------------------------------------
__global__ __launch_bounds__(256) void fixB(
    const int* __restrict__ amb_count,
    const float* __restrict__ WkT, const float* __restrict__ bk,
    const double* __restrict__ q64buf,
    double* __restrict__ ubuf, double* __restrict__ bkqbuf)
{
    int n = *amb_count; if (n > AMB_CAP) n = AMB_CAP;
    const int i = blockIdx.y;
    if (i >= n) return;
    const int tid = threadIdx.x;
    const int tl = tid & 63;
    const int js = tid >> 6;
    const int t = blockIdx.x * 64 + tl;

    __shared__ double qs[768];
    __shared__ double ps[4][64];
    const double* qrow = q64buf + (size_t)i * 768;
    for (int k = tid; k < 768; k += 256) qs[k] = qrow[k];
    __syncthreads();

    double a0 = 0.0, a1 = 0.0;
    const float* wp = WkT + t;
    const int j0 = js * 192;
#pragma unroll 8
    for (int k = 0; k < 192; k += 2) {
        a0 = fma((double)wp[(size_t)(j0 + k) * 768],     qs[j0 + k],     a0);
        a1 = fma((double)wp[(size_t)(j0 + k + 1) * 768], qs[j0 + k + 1], a1);
    }
    ps[js][tl] = a0 + a1;
    __syncthreads();
    if (js == 0)
        ubuf[(size_t)i * 768 + t] = (ps[0][tl] + ps[1][tl]) + (ps[2][tl] + ps[3][tl]);

    if (blockIdx.x == 0 && tid < 64) {
        double p = 0.0;
#pragma unroll
        for (int c = 0; c < 12; ++c) {
            int jj = tid + (c << 6);
            p = fma((double)bk[jj], qs[jj], p);
        }
#pragma unroll
        for (int off = 32; off; off >>= 1) p += __shfl_xor(p, off);
        if (tid == 0) bkqbuf[i] = p;
    }
}

// ---------------------------------------------------------------------------
// fixC: per amb row: 16 exact scores, f64 top-8, f64 softmax; coefficient
// combine over saved v rows -> dret[i][768] f32. grid (AMB_CAP).
// ---------------------------------------------------------------------------
__global__ __launch_bounds__(256) void fixC(
    const int* __restrict__ amb_count, const int* __restrict__ amb_grow,
    const float* __restrict__ x, const float* __restrict__ pm,
    const int* __restrict__ cand, const float* __restrict__ oldw,
    const double* __restrict__ ubuf, const double* __restrict__ bkqbuf,
    const f16* __restrict__ vsave, float* __restrict__ dret)
{
    int n = *amb_count; if (n > AMB_CAP) n = AMB_CAP;
    const int i = blockIdx.x;
    if (i >= n) return;
    const int tid = threadIdx.x;
    const int lane = tid & 63;
    const int wave = tid >> 6;
    const int grow = amb_grow[i];
    const float* xb = x + (size_t)(grow >> 12) * TT * 768;   // batch base

    __shared__ double us[768];
    __shared__ double cs_s[16];
    __shared__ float coef[16];

    const double* urow = ubuf + (size_t)i * 768;
    for (int t = tid; t < 768; t += 256) us[t] = urow[t];
    __syncthreads();

    const double ISQ = 1.0 / sqrt((double)DD);
    const double bkq = bkqbuf[i];
#pragma unroll
    for (int c = wave; c < 16; c += 4) {
        int s = cand[i * 16 + c];
        double p = 0.0;
        if (s < SS) {
            const float* xr = xb + (size_t)(4 * s) * 768;
#pragma unroll
            for (int t = 0; t < 12; ++t) {
                int j2 = lane + (t << 6);
                double sv = 0.25 * ((double)xr[j2] + (double)xr[j2 + 768] +
                                    (double)xr[j2 + 1536] + (double)xr[j2 + 2304]);
                p = fma(sv, us[j2], p);
            }
        } else {
            const float* pr = pm + (size_t)(s - SS) * 768;
#pragma unroll
            for (int t = 0; t < 12; ++t) {
                int j2 = lane + (t << 6);
                p = fma((double)pr[j2], us[j2], p);
            }
        }
#pragma unroll
        for (int off = 32; off; off >>= 1) p += __shfl_xor(p, off);
        if (lane == 0) cs_s[c] = (p + bkq) * ISQ;
    }
    __syncthreads();

    if (tid == 0) {
        double cs[16]; int ci[16];
        for (int c = 0; c < 16; ++c) { cs[c] = cs_s[c]; ci[c] = cand[i * 16 + c]; }
        unsigned used = 0;
        double sv[KTOP]; int sp[KTOP];
        for (int r = 0; r < KTOP; ++r) {
            int bi = -1;
            for (int c = 0; c < 16; ++c) {
                if (used & (1u << c)) continue;
                if (bi < 0 || cs[c] > cs[bi] ||
                    (cs[c] == cs[bi] && ci[c] < ci[bi])) bi = c;
            }
            used |= (1u << bi); sv[r] = cs[bi]; sp[r] = bi;
        }
        double mx = sv[0], es[KTOP], ssum = 0.0;
        for (int r = 0; r < KTOP; ++r) { es[r] = exp(sv[r] - mx); ssum += es[r]; }
        for (int c = 0; c < 16; ++c) coef[c] = (c < KTOP) ? -oldw[i * KTOP + c] : 0.f;
        for (int r = 0; r < KTOP; ++r) coef[sp[r]] += (float)(es[r] / ssum);
    }
    __syncthreads();

    const f16* vs = vsave + (size_t)i * 16 * 768;
    for (int j = tid; j < 768; j += 256) {
        float d = 0.f;
#pragma unroll
        for (int c = 0; c < 16; ++c) d += coef[c] * (float)vs[(size_t)c * 768 + j];
        dret[(size_t)i * 768 + j] = d;
    }
}

// ---------------------------------------------------------------------------
// fixD: out[grow][j] += RW * sum_t dret[i][t] * Wp[t][j].  grid (12, AMB_CAP).
// ---------------------------------------------------------------------------
__global__ __launch_bounds__(256) void fixD(
    const int* __restrict__ amb_count, const int* __restrict__ amb_grow,
    const float* __restrict__ dret, const float* __restrict__ Wp,
    float* __restrict__ out)
{
    int n = *amb_count; if (n > AMB_CAP) n = AMB_CAP;
    const int i = blockIdx.y;
    if (i >= n) return;
    const int tid = threadIdx.x;
    const int jl = tid & 63;
    const int ks = tid >> 6;
    const int j = blockIdx.x * 64 + jl;
    const int grow = amb_grow[i];

    __shared__ float ds[768];
    __shared__ float ps[4][64];
    for (int t = tid; t < 768; t += 256) ds[t] = dret[(size_t)i * 768 + t];
    __syncthreads();

    float a0 = 0.f, a1 = 0.f;
    const float* wp = Wp + j;
    const int k0 = ks * 192;
#pragma unroll 8
    for (int k = 0; k < 192; k += 2) {
        a0 = fmaf(ds[k0 + k],     wp[(size_t)(k0 + k) * 768],     a0);
        a1 = fmaf(ds[k0 + k + 1], wp[(size_t)(k0 + k + 1) * 768], a1);
    }
    ps[ks][jl] = a0 + a1;
    __syncthreads();
    if (ks == 0)
        out[(size_t)grow * 768 + j] +=
            RWEIGHT * ((ps[0][jl] + ps[1][jl]) + (ps[2][jl] + ps[3][jl]));
}

// ---------------------------------------------------------------------------
extern "C" void kernel_launch(void* const* d_in, const int* in_sizes, int n_in,
                              void* d_out, int out_size, void* d_ws, size_t ws_size,
                              hipStream_t stream)
{
    const float* x  = (const float*)d_in[0];
    const float* Wq = (const float*)d_in[1];
    const float* bq = (const float*)d_in[2];
    const float* Wk = (const float*)d_in[3];
    const float* bk = (const float*)d_in[4];
    const float* Wv = (const float*)d_in[5];
    const float* bv = (const float*)d_in[6];
    const float* Wp = (const float*)d_in[7];
    const float* bp = (const float*)d_in[8];
    const float* pm = (const float*)d_in[9];
    float* out = (float*)d_out;
    float* ws  = (float*)d_ws;

    const float inv_sqrt_d = (float)(1.0 / sqrt((double)DD));
    const size_t TD  = (size_t)TT * DD;
    const size_t SD  = (size_t)SS * DD;
    const size_t WSZ = (size_t)DD * DD;

    float* p = ws;
    float* WqT = p; p += WSZ;
    float* WkT = p; p += WSZ;
    float* WvT = p; p += WSZ;
    float* WpT = p; p += WSZ;
    float* slots_all = p; p += (size_t)BB * SD;
    f16* qh = (f16*)p; p += TD / 2;
    f16* qm = (f16*)p; p += TD / 2;
    f16* kh = (f16*)p; p += SD;
    f16* km = (f16*)p; p += SD;
    f16* v16 = (f16*)p; p += SD;
    f16* retrA = (f16*)p; p += TD / 2;
    f16* retrB = (f16*)p; p += TD / 2;
    double* q64buf = (double*)p; p += (size_t)AMB_CAP * DD * 2;
    double* ubuf   = (double*)p; p += (size_t)AMB_CAP * DD * 2;
    double* bkqbuf = (double*)p; p += AMB_CAP * 2;
    int* cand = (int*)p; p += (size_t)AMB_CAP * 16;
    float* oldw = p; p += (size_t)AMB_CAP * KTOP;
    f16* vsave = (f16*)p; p += (size_t)AMB_CAP * 16 * DD / 2;
    float* dret = p; p += (size_t)AMB_CAP * DD;
    int* ambc = (int*)p; p += 64;
    int* ambgrow = (int*)p; p += AMB_CAP;
    float* scores = p;
    size_t used = (size_t)(p - ws);

    long tc = TT;
    while (tc > 512 && (used + (size_t)tc * S2) * 4 > ws_size) tc >>= 1;

    transpose_all<<<dim3(24, 24, 4), 256, 0, stream>>>(
        Wq, Wk, Wv, Wp, WqT, WkT, WvT, WpT);
    zeroN<<<1, 64, 0, stream>>>(ambc);
    build_pooled_all<<<(BB * SS * DD) / 256, 256, 0, stream>>>(x, slots_all);

    // prolog: pm halves of k/v planes (rows S..2S-1), once.
    producers<<<96, 256, 0, stream>>>(
        nullptr, pm, nullptr, WqT, WkT, WvT, WpT, bq, bk, bv, bp,
        qh, qm, kh, km, v16, nullptr, 0, 48, SS);

    for (int b = 0; b < BB; ++b) {
        const float* xb = x + (size_t)b * TD;
        const float* slots_b = slots_all + (size_t)b * SD;
        f16* rcur = (b & 1) ? retrB : retrA;
        f16* rprev = (b & 1) ? retrA : retrB;
        int np = b ? 192 : 0;

        producers<<<288 + np, 256, 0, stream>>>(
            xb, slots_b, rprev, WqT, WkT, WvT, WpT, bq, bk, bv, bp,
            qh, qm, kh, km, v16, out + (size_t)(b - 1) * TD, 192, 48, 0);

        for (long t0 = 0; t0 < TT; t0 += tc) {
            scores_planes<<<dim3(16, tc / 128), 256, 0, stream>>>(
                qh + (size_t)t0 * DD, qm + (size_t)t0 * DD, kh, km,
                scores, inv_sqrt_d);
            select_combine<<<tc / 4, 256, 0, stream>>>(
                scores, v16, rcur + (size_t)t0 * DD, b * TT + (int)t0,
                ambc, ambgrow, cand, oldw, vsave);
        }
    }

    // tail: proj of last batch.
    f16* rlast = ((BB - 1) & 1) ? retrB : retrA;
    producers<<<192, 256, 0, stream>>>(
        nullptr, nullptr, rlast, WqT, WkT, WvT, WpT, bq, bk, bv, bp,
        qh, qm, kh, km, v16, out + (size_t)(BB - 1) * TD, 0, 0, 0);

    // deferred exact fixups (off the critical path, applied to out).
    fixA<<<dim3(12, AMB_CAP), 256, 0, stream>>>(ambc, ambgrow, x, Wq, bq, q64buf);
    fixB<<<dim3(12, AMB_CAP), 256, 0, stream>>>(ambc, WkT, bk, q64buf, ubuf, bkqbuf);
    fixC<<<AMB_CAP, 256, 0, stream>>>(ambc, ambgrow, x, pm, cand, oldw,
                                      ubuf, bkqbuf, vsave, dret);
    fixD<<<dim3(12, AMB_CAP), 256, 0, stream>>>(ambc, ambgrow, dret, Wp, out);
}